// Round 12
// baseline (372.592 us; speedup 1.0000x reference)
//
#include <hip/hip_runtime.h>
#include <hip/hip_bf16.h>

// ---------------------------------------------------------------------------
// Transformer block forward (B=4, T=2048, C=1024, F=4096).
// Engines:
//  - gemm256 (r9): 256x256, 512 thr, 4 phases/K-tile alt-quadrant, counted
//    vmcnt.  Used for qkv / ff1.
//  - gemm128 (r10): 128x128, 256 thr, 64 KiB LDS -> 2 blocks/CU.  Used for
//    scores (CSKIP) and ff2 (bias+resid epilogue).
//  - pv_k (new): gemm128 body with COMPLEMENTARY-PAIR KLIM scheduling:
//    block (bx, p, bz) computes row-tiles p (K=(p+1)*128) and 15-p
//    (K=(16-p)*128) -> constant 34 K-tiles/block, 256 balanced blocks
//    (fixes r11's 87us tail-imbalanced pv).
// All: T2 (row>>1)&3 swizzle (bank-conflict 0, verified r8+), T5 setprio,
// T1 bijective XCD swizzle, global_load_lds width-16 staging.
// ---------------------------------------------------------------------------

typedef __bf16 bf16x8_t __attribute__((ext_vector_type(8)));
typedef float f32x4_t __attribute__((ext_vector_type(4)));

__device__ __forceinline__ unsigned short f2bf(float f) {
    unsigned int u = __float_as_uint(f);
    u += 0x7fffu + ((u >> 16) & 1u);   // round-to-nearest-even
    return (unsigned short)(u >> 16);
}
__device__ __forceinline__ float bf2f(unsigned short u) {
    return __uint_as_float((unsigned int)u << 16);
}

__device__ __forceinline__ void gload16(const void* g, void* lds) {
    __builtin_amdgcn_global_load_lds(
        (const __attribute__((address_space(1))) unsigned int*)g,
        (__attribute__((address_space(3))) unsigned int*)lds, 16, 0, 0);
}

#define SB0() __builtin_amdgcn_sched_barrier(0)
#define BAR_LGKM() asm volatile("s_barrier\ns_waitcnt lgkmcnt(0)" ::: "memory")
#define BAR() asm volatile("s_barrier" ::: "memory")
#define VM4_BAR() asm volatile("s_waitcnt vmcnt(4)\ns_barrier" ::: "memory")
#define VM0_BAR() asm volatile("s_waitcnt vmcnt(0)\ns_barrier" ::: "memory")

enum { EPI_F32 = 0, EPI_BF16 = 1, EPI_BIAS_RELU_BF16 = 2, EPI_RESID_F32 = 3,
       EPI_BIAS_RESID_F32 = 4 };

// ======================= 256x256 engine (r9) ===============================
template <int EPI, bool CSKIP, bool KLIM>
__global__ __launch_bounds__(512, 2) void gemm256(
    const unsigned short* __restrict__ A,
    const unsigned short* __restrict__ Bm,
    void* __restrict__ Cout,
    const float* __restrict__ bias,
    const float* __restrict__ resid,
    int M, int N, int K, int lda, int ldb, float scale,
    long long batA, long long batB, long long batC, long long batR)
{
    __shared__ __align__(16) unsigned char lds[131072];

    const int gx = gridDim.x;
    const int nwg = gx * gridDim.y;
    int bl = blockIdx.y * gx + blockIdx.x;
    bl = (bl & 7) * (nwg >> 3) + (bl >> 3);
    const int bx = bl % gx, by = bl / gx;

    const int row0 = by * 256, col0 = bx * 256;
    if (CSKIP && col0 > row0) return;

    const int bz = blockIdx.z;
    const unsigned short* Ab = A + (long long)bz * batA + (long long)row0 * lda;
    const unsigned short* Bb = Bm + (long long)bz * batB + (long long)col0 * ldb;

    const int tid = threadIdx.x, lane = tid & 63, wid = tid >> 6;
    const int wrM = (wid >> 2) * 128;
    const int wcN = (wid & 3) * 64;
    const int lr = lane & 15, lg = lane >> 4;

    int Keff = K;
    if (KLIM) { int kl = row0 + 256; Keff = kl < K ? kl : K; }
    const int nkt = Keff >> 6;

    const int c0 = wid * 128 + lane;
    const int crow = c0 >> 2;
    const int sg = (c0 & 3) ^ ((c0 >> 3) & 3);
    const unsigned short* gA0 = Ab + (long long)crow * lda + sg * 8;
    const unsigned short* gA1 = gA0 + 16ll * lda;
    const unsigned short* gB0 = Bb + (long long)crow * ldb + sg * 8;
    const unsigned short* gB1 = gB0 + 16ll * ldb;

    const int sw = (lg ^ ((lr >> 1) & 3)) << 4;
    const int aoff = (wrM + lr) * 64 + sw;
    const int boff = 16384 + (wcN + lr) * 64 + sw;

    f32x4_t acc[8][4];
#pragma unroll
    for (int m = 0; m < 8; ++m)
#pragma unroll
        for (int n = 0; n < 4; ++n)
            acc[m][n] = (f32x4_t){0.f, 0.f, 0.f, 0.f};

    auto stageR = [&](int b, int r, int ktn) {
        const int kk = r >> 1, op = r & 1;
        const int ke = ktn * 64 + kk * 32;
        unsigned char* d = lds + b * 65536 + kk * 32768 + op * 16384 + wid * 2048;
        const unsigned short* g0 = (op ? gB0 : gA0) + ke;
        const unsigned short* g1 = (op ? gB1 : gA1) + ke;
        gload16(g0, d);
        gload16(g1, d + 1024);
    };

    bf16x8_t af[4], bv[4];
    auto dsA4 = [&](int b, int kk, int mq) {
        const unsigned char* u = lds + b * 65536 + kk * 32768;
#pragma unroll
        for (int j = 0; j < 4; ++j)
            af[j] = *(const bf16x8_t*)(u + aoff + (mq * 4 + j) * 1024);
    };
    auto dsB4 = [&](int b, int kk) {
        const unsigned char* u = lds + b * 65536 + kk * 32768;
#pragma unroll
        for (int n = 0; n < 4; ++n)
            bv[n] = *(const bf16x8_t*)(u + boff + n * 1024);
    };
    auto mf16 = [&](int mq) {
        __builtin_amdgcn_s_setprio(1);
#pragma unroll
        for (int j = 0; j < 4; ++j)
#pragma unroll
            for (int n = 0; n < 4; ++n)
                acc[mq * 4 + j][n] = __builtin_amdgcn_mfma_f32_16x16x32_bf16(
                    af[j], bv[n], acc[mq * 4 + j][n], 0, 0, 0);
        __builtin_amdgcn_s_setprio(0);
    };

    stageR(0, 0, 0); stageR(0, 1, 0); stageR(0, 2, 0); stageR(0, 3, 0);
    VM4_BAR();

    int kt = 0;
    for (; kt < nkt - 1; ++kt) {
        const int buf = kt & 1, nb = buf ^ 1;
        dsA4(buf, 0, 0); dsB4(buf, 0);
        stageR(nb, 0, kt + 1);
        BAR_LGKM(); SB0();
        mf16(0); SB0();
        BAR();
        dsA4(buf, 0, 1);
        stageR(nb, 1, kt + 1);
        BAR_LGKM(); SB0();
        mf16(1); SB0();
        VM4_BAR();
        dsA4(buf, 1, 0); dsB4(buf, 1);
        stageR(nb, 2, kt + 1);
        BAR_LGKM(); SB0();
        mf16(0); SB0();
        BAR();
        dsA4(buf, 1, 1);
        stageR(nb, 3, kt + 1);
        BAR_LGKM(); SB0();
        mf16(1); SB0();
        VM4_BAR();
    }
    {
        const int buf = kt & 1;
        dsA4(buf, 0, 0); dsB4(buf, 0);
        BAR_LGKM(); SB0();
        mf16(0); SB0();
        BAR();
        dsA4(buf, 0, 1);
        BAR_LGKM(); SB0();
        mf16(1); SB0();
        VM0_BAR();
        dsA4(buf, 1, 0); dsB4(buf, 1);
        BAR_LGKM(); SB0();
        mf16(0); SB0();
        BAR();
        dsA4(buf, 1, 1);
        BAR_LGKM(); SB0();
        mf16(1); SB0();
    }

    const int ldc = N;
    float* Cf = (float*)Cout + (long long)bz * batC;
    unsigned short* Cb = (unsigned short*)Cout + (long long)bz * batC;
    const float* R = nullptr;
    if constexpr (EPI == EPI_RESID_F32 || EPI == EPI_BIAS_RESID_F32)
        R = resid + (long long)bz * batR;

#pragma unroll
    for (int m = 0; m < 8; ++m)
#pragma unroll
        for (int n = 0; n < 4; ++n)
#pragma unroll
            for (int j = 0; j < 4; ++j) {
                const int row = row0 + wrM + m * 16 + lg * 4 + j;
                const int col = col0 + wcN + n * 16 + lr;
                const long long idx = (long long)row * ldc + col;
                float v = acc[m][n][j] * scale;
                if constexpr (EPI == EPI_F32) {
                    Cf[idx] = v;
                } else if constexpr (EPI == EPI_BF16) {
                    Cb[idx] = f2bf(v);
                } else if constexpr (EPI == EPI_BIAS_RELU_BF16) {
                    v += bias[col];
                    v = v > 0.f ? v : 0.f;
                    Cb[idx] = f2bf(v);
                } else if constexpr (EPI == EPI_RESID_F32) {
                    Cf[idx] = v + R[idx];
                } else {
                    Cf[idx] = v + bias[col] + R[idx];
                }
            }
}

// ======================= 128x128 engine (r10) ==============================
template <int EPI, bool CSKIP, bool KLIM>
__global__ __launch_bounds__(256, 2) void gemm128(
    const unsigned short* __restrict__ A,
    const unsigned short* __restrict__ Bm,
    void* __restrict__ Cout,
    const float* __restrict__ bias,
    const float* __restrict__ resid,
    int M, int N, int K, int lda, int ldb, float scale,
    long long batA, long long batB, long long batC, long long batR)
{
    __shared__ __align__(16) unsigned char lds[65536];

    const int gx = gridDim.x;
    const int nwg = gx * gridDim.y;
    int bl = blockIdx.y * gx + blockIdx.x;
    bl = (bl & 7) * (nwg >> 3) + (bl >> 3);
    const int bx = bl % gx, by = bl / gx;

    const int row0 = by * 128, col0 = bx * 128;
    if (CSKIP && col0 > row0) return;

    const int bz = blockIdx.z;
    const unsigned short* Ab = A + (long long)bz * batA + (long long)row0 * lda;
    const unsigned short* Bb = Bm + (long long)bz * batB + (long long)col0 * ldb;

    const int tid = threadIdx.x, lane = tid & 63, wid = tid >> 6;
    const int wrM = (wid >> 1) * 64;
    const int wcN = (wid & 1) * 64;
    const int lr = lane & 15, lg = lane >> 4;

    int Keff = K;
    if (KLIM) { int kl = row0 + 128; Keff = kl < K ? kl : K; }
    const int nkt = Keff >> 6;

    const int c0 = wid * 128 + lane;
    const int crow = c0 >> 2;
    const int sg = (c0 & 3) ^ ((c0 >> 3) & 3);
    const unsigned short* gA0 = Ab + (long long)crow * lda + sg * 8;
    const unsigned short* gA1 = gA0 + 16ll * lda;
    const unsigned short* gB0 = Bb + (long long)crow * ldb + sg * 8;
    const unsigned short* gB1 = gB0 + 16ll * ldb;

    const int sw = (lg ^ ((lr >> 1) & 3)) << 4;
    const int aoff = (wrM + lr) * 64 + sw;
    const int boff = 8192 + (wcN + lr) * 64 + sw;

    f32x4_t acc[4][4];
#pragma unroll
    for (int m = 0; m < 4; ++m)
#pragma unroll
        for (int n = 0; n < 4; ++n)
            acc[m][n] = (f32x4_t){0.f, 0.f, 0.f, 0.f};

    auto stage2 = [&](int b, int kk, int ktn) {
        const int ke = ktn * 64 + kk * 32;
        unsigned char* uA = lds + b * 32768 + kk * 16384 + wid * 2048;
        unsigned char* uB = uA + 8192;
        gload16(gA0 + ke, uA);
        gload16(gA1 + ke, uA + 1024);
        gload16(gB0 + ke, uB);
        gload16(gB1 + ke, uB + 1024);
    };

    bf16x8_t af[4], bv[4];
    auto dsAB = [&](int b, int kk) {
        const unsigned char* u = lds + b * 32768 + kk * 16384;
#pragma unroll
        for (int m = 0; m < 4; ++m)
            af[m] = *(const bf16x8_t*)(u + aoff + m * 1024);
#pragma unroll
        for (int n = 0; n < 4; ++n)
            bv[n] = *(const bf16x8_t*)(u + boff + n * 1024);
    };
    auto mf16 = [&]() {
        __builtin_amdgcn_s_setprio(1);
#pragma unroll
        for (int m = 0; m < 4; ++m)
#pragma unroll
            for (int n = 0; n < 4; ++n)
                acc[m][n] = __builtin_amdgcn_mfma_f32_16x16x32_bf16(
                    af[m], bv[n], acc[m][n], 0, 0, 0);
        __builtin_amdgcn_s_setprio(0);
    };

    stage2(0, 0, 0); stage2(0, 1, 0);
    VM4_BAR();

    int kt = 0;
    for (; kt < nkt - 1; ++kt) {
        const int buf = kt & 1, nb = buf ^ 1;
        dsAB(buf, 0);
        stage2(nb, 0, kt + 1);
        BAR_LGKM(); SB0();
        mf16(); SB0();
        VM4_BAR();
        dsAB(buf, 1);
        stage2(nb, 1, kt + 1);
        BAR_LGKM(); SB0();
        mf16(); SB0();
        VM4_BAR();
    }
    {
        const int buf = kt & 1;
        dsAB(buf, 0);
        BAR_LGKM(); SB0();
        mf16(); SB0();
        VM0_BAR();
        dsAB(buf, 1);
        BAR_LGKM(); SB0();
        mf16(); SB0();
    }

    const int ldc = N;
    float* Cf = (float*)Cout + (long long)bz * batC;
    unsigned short* Cb = (unsigned short*)Cout + (long long)bz * batC;
    const float* R = nullptr;
    if constexpr (EPI == EPI_RESID_F32 || EPI == EPI_BIAS_RESID_F32)
        R = resid + (long long)bz * batR;

#pragma unroll
    for (int m = 0; m < 4; ++m)
#pragma unroll
        for (int n = 0; n < 4; ++n)
#pragma unroll
            for (int j = 0; j < 4; ++j) {
                const int row = row0 + wrM + m * 16 + lg * 4 + j;
                const int col = col0 + wcN + n * 16 + lr;
                const long long idx = (long long)row * ldc + col;
                float v = acc[m][n][j] * scale;
                if constexpr (EPI == EPI_F32) {
                    Cf[idx] = v;
                } else if constexpr (EPI == EPI_BF16) {
                    Cb[idx] = f2bf(v);
                } else if constexpr (EPI == EPI_BIAS_RELU_BF16) {
                    v += bias[col];
                    v = v > 0.f ? v : 0.f;
                    Cb[idx] = f2bf(v);
                } else if constexpr (EPI == EPI_RESID_F32) {
                    Cf[idx] = v + R[idx];
                } else {
                    Cf[idx] = v + bias[col] + R[idx];
                }
            }
}

// ================== pv: paired-KLIM 128x128 engine =========================
// Block (bx, p, bz): row-tiles p (K=(p+1)*128) and 15-p (K=(16-p)*128);
// every block does exactly 34 K-tiles -> balanced.  xres = x + P @ v.
__global__ __launch_bounds__(256, 2) void pv_k(
    const unsigned short* __restrict__ Pm,   // [B][T][T] bf16, row zero-pad
    const unsigned short* __restrict__ vT,   // [C][B*T]
    float* __restrict__ xres,
    const float* __restrict__ x,
    int Tt, int Cc, int BT)
{
    __shared__ __align__(16) unsigned char lds[65536];

    const int gx = gridDim.x;                // 8
    const int nwg = gx * gridDim.y;          // 64
    int bl = blockIdx.y * gx + blockIdx.x;
    bl = (bl & 7) * (nwg >> 3) + (bl >> 3);
    const int bx = bl % gx, by = bl / gx;    // by = pair index 0..7
    const int bz = blockIdx.z;

    const int col0 = bx * 128;
    const int tid = threadIdx.x, lane = tid & 63, wid = tid >> 6;
    const int wrM = (wid >> 1) * 64;
    const int wcN = (wid & 1) * 64;
    const int lr = lane & 15, lg = lane >> 4;

    const int c0 = wid * 128 + lane;
    const int crow = c0 >> 2;
    const int sg = (c0 & 3) ^ ((c0 >> 3) & 3);

    const int lda = Tt, ldb = BT, ldc = Cc;
    const unsigned short* Bb = vT + (long long)bz * Tt + (long long)col0 * ldb;
    const unsigned short* gB0 = Bb + (long long)crow * ldb + sg * 8;
    const unsigned short* gB1 = gB0 + 16ll * ldb;

    const int sw = (lg ^ ((lr >> 1) & 3)) << 4;
    const int aoff = (wrM + lr) * 64 + sw;
    const int boff = 8192 + (wcN + lr) * 64 + sw;

    bf16x8_t af[4], bv[4];
    auto dsAB = [&](int b, int kk) {
        const unsigned char* u = lds + b * 32768 + kk * 16384;
#pragma unroll
        for (int m = 0; m < 4; ++m)
            af[m] = *(const bf16x8_t*)(u + aoff + m * 1024);
#pragma unroll
        for (int n = 0; n < 4; ++n)
            bv[n] = *(const bf16x8_t*)(u + boff + n * 1024);
    };

    float* Cf = xres + (long long)bz * Tt * Cc;
    const float* R = x + (long long)bz * Tt * Cc;

    for (int pass = 0; pass < 2; ++pass) {
        const int by_eff = pass ? (15 - by) : by;
        const int row0 = by_eff * 128;
        const int nkt = (row0 + 128) >> 6;   // 2..32, balanced across passes

        const unsigned short* Ab = Pm + (long long)bz * Tt * Tt + (long long)row0 * lda;
        const unsigned short* gA0 = Ab + (long long)crow * lda + sg * 8;
        const unsigned short* gA1 = gA0 + 16ll * lda;

        auto stage2 = [&](int b, int kk, int ktn) {
            const int ke = ktn * 64 + kk * 32;
            unsigned char* uA = lds + b * 32768 + kk * 16384 + wid * 2048;
            unsigned char* uB = uA + 8192;
            gload16(gA0 + ke, uA);
            gload16(gA1 + ke, uA + 1024);
            gload16(gB0 + ke, uB);
            gload16(gB1 + ke, uB + 1024);
        };

        f32x4_t acc[4][4];
#pragma unroll
        for (int m = 0; m < 4; ++m)
#pragma unroll
            for (int n = 0; n < 4; ++n)
                acc[m][n] = (f32x4_t){0.f, 0.f, 0.f, 0.f};

        auto mf16 = [&]() {
            __builtin_amdgcn_s_setprio(1);
#pragma unroll
            for (int m = 0; m < 4; ++m)
#pragma unroll
                for (int n = 0; n < 4; ++n)
                    acc[m][n] = __builtin_amdgcn_mfma_f32_16x16x32_bf16(
                        af[m], bv[n], acc[m][n], 0, 0, 0);
            __builtin_amdgcn_s_setprio(0);
        };

        if (pass) BAR();   // all waves done reading LDS from pass 0
        // prologue (vmcnt FIFO: older epilogue stores drain first -> safe)
        stage2(0, 0, 0); stage2(0, 1, 0);
        VM4_BAR();

        int kt = 0;
        for (; kt < nkt - 1; ++kt) {
            const int buf = kt & 1, nb = buf ^ 1;
            dsAB(buf, 0);
            stage2(nb, 0, kt + 1);
            BAR_LGKM(); SB0();
            mf16(); SB0();
            VM4_BAR();
            dsAB(buf, 1);
            stage2(nb, 1, kt + 1);
            BAR_LGKM(); SB0();
            mf16(); SB0();
            VM4_BAR();
        }
        {
            const int buf = kt & 1;
            dsAB(buf, 0);
            BAR_LGKM(); SB0();
            mf16(); SB0();
            VM0_BAR();
            dsAB(buf, 1);
            BAR_LGKM(); SB0();
            mf16(); SB0();
        }

#pragma unroll
        for (int m = 0; m < 4; ++m)
#pragma unroll
            for (int n = 0; n < 4; ++n)
#pragma unroll
                for (int j = 0; j < 4; ++j) {
                    const int row = row0 + wrM + m * 16 + lg * 4 + j;
                    const int col = col0 + wcN + n * 16 + lr;
                    const long long idx = (long long)row * ldc + col;
                    Cf[idx] = acc[m][n][j] + R[idx];
                }
    }
}

// ------------- transpose + fp32->bf16 convert: in [R][Cc] -> out [Cc][R] ----
__global__ __launch_bounds__(256) void tconv_k(
    const float* __restrict__ in, unsigned short* __restrict__ out,
    int R, int Cc)
{
    __shared__ float t[64][65];
    const int r0 = blockIdx.y * 64, c0 = blockIdx.x * 64;
    const int tid = threadIdx.x;
    const int a = tid >> 4;
    const int b = tid & 15;
#pragma unroll
    for (int i = 0; i < 4; ++i) {
        const int row = a + i * 16;
        float4 v = *(const float4*)(in + (long long)(r0 + row) * Cc + c0 + b * 4);
        t[row][b * 4 + 0] = v.x; t[row][b * 4 + 1] = v.y;
        t[row][b * 4 + 2] = v.z; t[row][b * 4 + 3] = v.w;
    }
    __syncthreads();
#pragma unroll
    for (int i = 0; i < 4; ++i) {
        const int oc = a + i * 16;
        ushort4 o;
        o.x = f2bf(t[b * 4 + 0][oc]);
        o.y = f2bf(t[b * 4 + 1][oc]);
        o.z = f2bf(t[b * 4 + 2][oc]);
        o.w = f2bf(t[b * 4 + 3][oc]);
        *(ushort4*)(out + (long long)(c0 + oc) * R + r0 + b * 4) = o;
    }
}

// ------ bf16 transpose of the v-slice: qkv[8192][3072]@col2048 -> vT[1024][8192]
__global__ __launch_bounds__(256) void vtrans_k(
    const unsigned short* __restrict__ in, unsigned short* __restrict__ out)
{
    __shared__ unsigned short t[64][72];
    const int r0 = blockIdx.x * 64;
    const int c0 = blockIdx.y * 64;
    const int tid = threadIdx.x;
#pragma unroll
    for (int i = 0; i < 2; ++i) {
        const int ch = tid * 2 + i;
        const int row = ch >> 3, cs = ch & 7;
        int4 v = *(const int4*)(in + (long long)(r0 + row) * 3072 + 2048 + c0 + cs * 8);
        *(int4*)&t[row][cs * 8] = v;
    }
    __syncthreads();
#pragma unroll
    for (int i = 0; i < 2; ++i) {
        const int w = tid * 2 + i;
        const int oc = w >> 3, orc = w & 7;
        unsigned short tmp[8];
#pragma unroll
        for (int j = 0; j < 8; ++j) tmp[j] = t[orc * 8 + j][oc];
        *(int4*)(out + (long long)(c0 + oc) * 8192 + r0 + orc * 8) = *(const int4*)tmp;
    }
}

// ---------------- LayerNorm: one wave per 1024-elem row ---------------------
__global__ __launch_bounds__(256) void ln_k(
    const float* __restrict__ x, const float* __restrict__ g,
    const float* __restrict__ be, unsigned short* __restrict__ out)
{
    const int wv = threadIdx.x >> 6, lane = threadIdx.x & 63;
    const long long row = blockIdx.x * 4 + wv;
    const float* xr = x + row * 1024;
    float4 v[4];
    float s = 0.f, q = 0.f;
#pragma unroll
    for (int j = 0; j < 4; ++j) {
        v[j] = *(const float4*)(xr + j * 256 + lane * 4);
        s += v[j].x + v[j].y + v[j].z + v[j].w;
        q += v[j].x * v[j].x + v[j].y * v[j].y + v[j].z * v[j].z + v[j].w * v[j].w;
    }
#pragma unroll
    for (int off = 32; off > 0; off >>= 1) {
        s += __shfl_xor(s, off);
        q += __shfl_xor(q, off);
    }
    const float mean = s * (1.0f / 1024.0f);
    const float var  = q * (1.0f / 1024.0f) - mean * mean;
    const float rstd = rsqrtf(var + 1e-5f);
#pragma unroll
    for (int j = 0; j < 4; ++j) {
        float4 gv = *(const float4*)(g + j * 256 + lane * 4);
        float4 bv = *(const float4*)(be + j * 256 + lane * 4);
        ushort4 o;
        o.x = f2bf((v[j].x - mean) * rstd * gv.x + bv.x);
        o.y = f2bf((v[j].y - mean) * rstd * gv.y + bv.y);
        o.z = f2bf((v[j].z - mean) * rstd * gv.z + bv.z);
        o.w = f2bf((v[j].w - mean) * rstd * gv.w + bv.w);
        *(ushort4*)(out + row * 1024 + j * 256 + lane * 4) = o;
    }
}

// ------------- causal row softmax: S bf16 -> P bf16 (zero-padded) ----------
__global__ __launch_bounds__(256) void softmax_k(
    const unsigned short* __restrict__ S, unsigned short* __restrict__ P, int T)
{
    __shared__ float rowl[2048];
    __shared__ float sred[4];
    const int t = blockIdx.x;
    const long long base = ((long long)blockIdx.y * T + t) * (long long)T;
    const unsigned short* srow = S + base;
    unsigned short* prow = P + base;
    const int n = t + 1;                       // valid causal length
    const int lim = ((t >> 7) + 1) << 7;       // zero-fill to 128 boundary
    const int tid = threadIdx.x;

    const int n8 = n >> 3;
    for (int i = tid; i < n8; i += 256) {
        int4 r = ((const int4*)srow)[i];
        const unsigned short* u = (const unsigned short*)&r;
#pragma unroll
        for (int j = 0; j < 8; ++j) rowl[i * 8 + j] = bf2f(u[j]);
    }
    for (int i = (n8 << 3) + tid; i < n; i += 256) rowl[i] = bf2f(srow[i]);
    __syncthreads();

    float mx = -3.0e38f;
    for (int i = tid; i < n; i += 256) mx = fmaxf(mx, rowl[i]);
#pragma unroll
    for (int off = 32; off > 0; off >>= 1) mx = fmaxf(mx, __shfl_xor(mx, off));
    if ((tid & 63) == 0) sred[tid >> 6] = mx;
    __syncthreads();
    mx = fmaxf(fmaxf(sred[0], sred[1]), fmaxf(sred[2], sred[3]));
    __syncthreads();

    float sum = 0.f;
    for (int i = tid; i < n; i += 256) {
        float e = __expf(rowl[i] - mx);
        rowl[i] = e;
        sum += e;
    }
#pragma unroll
    for (int off = 32; off > 0; off >>= 1) sum += __shfl_xor(sum, off);
    if ((tid & 63) == 0) sred[tid >> 6] = sum;
    __syncthreads();
    sum = sred[0] + sred[1] + sred[2] + sred[3];
    const float inv = 1.0f / sum;

    for (int i = tid; i < n; i += 256) prow[i] = f2bf(rowl[i] * inv);
    for (int i = n + tid; i < lim; i += 256) prow[i] = 0;
}

// ---------------------------------------------------------------------------
extern "C" void kernel_launch(void* const* d_in, const int* in_sizes, int n_in,
                              void* d_out, int out_size, void* d_ws, size_t ws_size,
                              hipStream_t stream)
{
    const int B = 4, T = 2048, C = 1024, F = 4096;
    const float* x   = (const float*)d_in[0];
    const float* Wk  = (const float*)d_in[1];
    const float* Wq  = (const float*)d_in[2];
    const float* Wv  = (const float*)d_in[3];
    const float* W1  = (const float*)d_in[4];
    const float* b1  = (const float*)d_in[5];
    const float* W2  = (const float*)d_in[6];
    const float* b2  = (const float*)d_in[7];
    const float* g1  = (const float*)d_in[8];
    const float* be1 = (const float*)d_in[9];
    const float* g2  = (const float*)d_in[10];
    const float* be2 = (const float*)d_in[11];

    char* ws = (char*)d_ws;
    const size_t MB = 1ull << 20;
    unsigned short* h     = (unsigned short*)(ws + 0);         // 16 MiB
    unsigned short* qkv   = (unsigned short*)(ws + 16 * MB);   // 48 MiB [8192][3072]
    unsigned short* vT    = (unsigned short*)(ws + 64 * MB);   // 16 MiB [1024][8192]
    float*          xres  = (float*)(ws + 80 * MB);            // 32 MiB
    unsigned short* S     = (unsigned short*)(ws + 112 * MB);  // 32 MiB bf16 [B][T][T]
    unsigned short* P     = (unsigned short*)(ws + 144 * MB);  // 32 MiB
    unsigned short* ff1   = (unsigned short*)(ws + 112 * MB);  // 64 MiB (aliases S+P)
    unsigned short* wqkvT = (unsigned short*)(ws + 176 * MB);  // 6 MiB [3C][C]
    unsigned short* w1T   = (unsigned short*)(ws + 182 * MB);  // 8 MiB [F][C]
    unsigned short* w2T   = (unsigned short*)(ws + 190 * MB);  // 8 MiB [C][F]

    // transposed weight converts (q,k,v fused into wqkvT)
    tconv_k<<<dim3(16, 16), 256, 0, stream>>>(Wq, wqkvT, C, C);
    tconv_k<<<dim3(16, 16), 256, 0, stream>>>(Wk, wqkvT + C * C, C, C);
    tconv_k<<<dim3(16, 16), 256, 0, stream>>>(Wv, wqkvT + 2 * C * C, C, C);
    tconv_k<<<dim3(64, 16), 256, 0, stream>>>(W1, w1T, C, F);
    tconv_k<<<dim3(16, 64), 256, 0, stream>>>(W2, w2T, F, C);

    // LN1
    ln_k<<<dim3(B * T / 4), 256, 0, stream>>>(x, g1, be1, h);

    // [q|k|v] = h @ [Wq|Wk|Wv]   (M=8192, N=3072, K=1024) -> 384 blocks @256²
    dim3 gqkv(3 * C / 256, (B * T) / 256, 1);
    gemm256<EPI_BF16, false, false><<<gqkv, 512, 0, stream>>>(
        h, wqkvT, qkv, nullptr, nullptr, B * T, 3 * C, C, C, C, 1.0f, 0, 0, 0, 0);

    // vT = transpose of v-slice
    vtrans_k<<<dim3(B * T / 64, C / 64), 256, 0, stream>>>(qkv, vT);

    // S = q @ k^T / 32 (bf16; causal tiles only) -> 544 alive @128² (2/CU)
    dim3 gsc(T / 128, T / 128, B);
    gemm128<EPI_BF16, true, false><<<gsc, 256, 0, stream>>>(
        qkv, qkv + C, S, nullptr, nullptr, T, T, C, 3 * C, 3 * C, 0.03125f,
        (long long)T * 3 * C, (long long)T * 3 * C, (long long)T * T, 0);

    // P = causal softmax(S)
    softmax_k<<<dim3(T, B), 256, 0, stream>>>(S, P, T);

    // xres = x + P @ v : paired-KLIM engine, 256 balanced blocks
    pv_k<<<dim3(C / 128, 8, B), 256, 0, stream>>>(
        P, vT, xres, x, T, C, B * T);

    // LN2
    ln_k<<<dim3(B * T / 4), 256, 0, stream>>>(xres, g2, be2, h);

    // ff1 = relu(h @ W1 + b1)   (M=8192, N=4096, K=1024) -> 512 blocks @256²
    dim3 gf1(F / 256, (B * T) / 256, 1);
    gemm256<EPI_BIAS_RELU_BF16, false, false><<<gf1, 512, 0, stream>>>(
        h, w1T, ff1, b1, nullptr, B * T, F, C, C, C, 1.0f, 0, 0, 0, 0);

    // out = xres + ff1 @ W2 + b2   (M=8192, N=1024, K=4096) -> 512 blocks @128²
    dim3 gf2(C / 128, (B * T) / 128, 1);
    gemm128<EPI_BIAS_RESID_F32, false, false><<<gf2, 256, 0, stream>>>(
        ff1, w2T, (float*)d_out, b2, xres, B * T, C, F, F, F, 1.0f, 0, 0, 0, 0);
}

// Round 13
// 358.101 us; speedup vs baseline: 1.0405x; 1.0405x over previous
//
#include <hip/hip_runtime.h>
#include <hip/hip_bf16.h>

// ---------------------------------------------------------------------------
// Transformer block forward (B=4, T=2048, C=1024, F=4096).
// Engines:
//  - gemm256 (r9): 256x256, 512 thr, 4 phases/K-tile alt-quadrant, counted
//    vmcnt.  Used for qkv / scores / ff1.
//  - gemm128 (r10): 128x128, 256 thr, 64 KiB LDS -> 2 blocks/CU.  Used for
//    ff2 (bias+resid epilogue).
//  - pv_k (r12): gemm128 body, complementary-pair KLIM scheduling (balanced
//    34 K-tiles/block, 256 blocks).
// Softmax: warp-per-row, register-resident (no LDS, no barriers), causal-
// trimmed loads.
// All GEMMs: T2 (row>>1)&3 swizzle (bank-conflict 0, verified r8+), T5
// setprio, T1 bijective XCD swizzle, global_load_lds width-16 staging.
// ---------------------------------------------------------------------------

typedef __bf16 bf16x8_t __attribute__((ext_vector_type(8)));
typedef float f32x4_t __attribute__((ext_vector_type(4)));

__device__ __forceinline__ unsigned short f2bf(float f) {
    unsigned int u = __float_as_uint(f);
    u += 0x7fffu + ((u >> 16) & 1u);   // round-to-nearest-even
    return (unsigned short)(u >> 16);
}
__device__ __forceinline__ float bf2f(unsigned short u) {
    return __uint_as_float((unsigned int)u << 16);
}

__device__ __forceinline__ void gload16(const void* g, void* lds) {
    __builtin_amdgcn_global_load_lds(
        (const __attribute__((address_space(1))) unsigned int*)g,
        (__attribute__((address_space(3))) unsigned int*)lds, 16, 0, 0);
}

#define SB0() __builtin_amdgcn_sched_barrier(0)
#define BAR_LGKM() asm volatile("s_barrier\ns_waitcnt lgkmcnt(0)" ::: "memory")
#define BAR() asm volatile("s_barrier" ::: "memory")
#define VM4_BAR() asm volatile("s_waitcnt vmcnt(4)\ns_barrier" ::: "memory")
#define VM0_BAR() asm volatile("s_waitcnt vmcnt(0)\ns_barrier" ::: "memory")

enum { EPI_F32 = 0, EPI_BF16 = 1, EPI_BIAS_RELU_BF16 = 2, EPI_RESID_F32 = 3,
       EPI_BIAS_RESID_F32 = 4 };

// ======================= 256x256 engine (r9) ===============================
template <int EPI, bool CSKIP, bool KLIM>
__global__ __launch_bounds__(512, 2) void gemm256(
    const unsigned short* __restrict__ A,
    const unsigned short* __restrict__ Bm,
    void* __restrict__ Cout,
    const float* __restrict__ bias,
    const float* __restrict__ resid,
    int M, int N, int K, int lda, int ldb, float scale,
    long long batA, long long batB, long long batC, long long batR)
{
    __shared__ __align__(16) unsigned char lds[131072];

    const int gx = gridDim.x;
    const int nwg = gx * gridDim.y;
    int bl = blockIdx.y * gx + blockIdx.x;
    bl = (bl & 7) * (nwg >> 3) + (bl >> 3);
    const int bx = bl % gx, by = bl / gx;

    const int row0 = by * 256, col0 = bx * 256;
    if (CSKIP && col0 > row0) return;

    const int bz = blockIdx.z;
    const unsigned short* Ab = A + (long long)bz * batA + (long long)row0 * lda;
    const unsigned short* Bb = Bm + (long long)bz * batB + (long long)col0 * ldb;

    const int tid = threadIdx.x, lane = tid & 63, wid = tid >> 6;
    const int wrM = (wid >> 2) * 128;
    const int wcN = (wid & 3) * 64;
    const int lr = lane & 15, lg = lane >> 4;

    int Keff = K;
    if (KLIM) { int kl = row0 + 256; Keff = kl < K ? kl : K; }
    const int nkt = Keff >> 6;

    const int c0 = wid * 128 + lane;
    const int crow = c0 >> 2;
    const int sg = (c0 & 3) ^ ((c0 >> 3) & 3);
    const unsigned short* gA0 = Ab + (long long)crow * lda + sg * 8;
    const unsigned short* gA1 = gA0 + 16ll * lda;
    const unsigned short* gB0 = Bb + (long long)crow * ldb + sg * 8;
    const unsigned short* gB1 = gB0 + 16ll * ldb;

    const int sw = (lg ^ ((lr >> 1) & 3)) << 4;
    const int aoff = (wrM + lr) * 64 + sw;
    const int boff = 16384 + (wcN + lr) * 64 + sw;

    f32x4_t acc[8][4];
#pragma unroll
    for (int m = 0; m < 8; ++m)
#pragma unroll
        for (int n = 0; n < 4; ++n)
            acc[m][n] = (f32x4_t){0.f, 0.f, 0.f, 0.f};

    auto stageR = [&](int b, int r, int ktn) {
        const int kk = r >> 1, op = r & 1;
        const int ke = ktn * 64 + kk * 32;
        unsigned char* d = lds + b * 65536 + kk * 32768 + op * 16384 + wid * 2048;
        const unsigned short* g0 = (op ? gB0 : gA0) + ke;
        const unsigned short* g1 = (op ? gB1 : gA1) + ke;
        gload16(g0, d);
        gload16(g1, d + 1024);
    };

    bf16x8_t af[4], bv[4];
    auto dsA4 = [&](int b, int kk, int mq) {
        const unsigned char* u = lds + b * 65536 + kk * 32768;
#pragma unroll
        for (int j = 0; j < 4; ++j)
            af[j] = *(const bf16x8_t*)(u + aoff + (mq * 4 + j) * 1024);
    };
    auto dsB4 = [&](int b, int kk) {
        const unsigned char* u = lds + b * 65536 + kk * 32768;
#pragma unroll
        for (int n = 0; n < 4; ++n)
            bv[n] = *(const bf16x8_t*)(u + boff + n * 1024);
    };
    auto mf16 = [&](int mq) {
        __builtin_amdgcn_s_setprio(1);
#pragma unroll
        for (int j = 0; j < 4; ++j)
#pragma unroll
            for (int n = 0; n < 4; ++n)
                acc[mq * 4 + j][n] = __builtin_amdgcn_mfma_f32_16x16x32_bf16(
                    af[j], bv[n], acc[mq * 4 + j][n], 0, 0, 0);
        __builtin_amdgcn_s_setprio(0);
    };

    stageR(0, 0, 0); stageR(0, 1, 0); stageR(0, 2, 0); stageR(0, 3, 0);
    VM4_BAR();

    int kt = 0;
    for (; kt < nkt - 1; ++kt) {
        const int buf = kt & 1, nb = buf ^ 1;
        dsA4(buf, 0, 0); dsB4(buf, 0);
        stageR(nb, 0, kt + 1);
        BAR_LGKM(); SB0();
        mf16(0); SB0();
        BAR();
        dsA4(buf, 0, 1);
        stageR(nb, 1, kt + 1);
        BAR_LGKM(); SB0();
        mf16(1); SB0();
        VM4_BAR();
        dsA4(buf, 1, 0); dsB4(buf, 1);
        stageR(nb, 2, kt + 1);
        BAR_LGKM(); SB0();
        mf16(0); SB0();
        BAR();
        dsA4(buf, 1, 1);
        stageR(nb, 3, kt + 1);
        BAR_LGKM(); SB0();
        mf16(1); SB0();
        VM4_BAR();
    }
    {
        const int buf = kt & 1;
        dsA4(buf, 0, 0); dsB4(buf, 0);
        BAR_LGKM(); SB0();
        mf16(0); SB0();
        BAR();
        dsA4(buf, 0, 1);
        BAR_LGKM(); SB0();
        mf16(1); SB0();
        VM0_BAR();
        dsA4(buf, 1, 0); dsB4(buf, 1);
        BAR_LGKM(); SB0();
        mf16(0); SB0();
        BAR();
        dsA4(buf, 1, 1);
        BAR_LGKM(); SB0();
        mf16(1); SB0();
    }

    const int ldc = N;
    float* Cf = (float*)Cout + (long long)bz * batC;
    unsigned short* Cb = (unsigned short*)Cout + (long long)bz * batC;
    const float* R = nullptr;
    if constexpr (EPI == EPI_RESID_F32 || EPI == EPI_BIAS_RESID_F32)
        R = resid + (long long)bz * batR;

#pragma unroll
    for (int m = 0; m < 8; ++m)
#pragma unroll
        for (int n = 0; n < 4; ++n)
#pragma unroll
            for (int j = 0; j < 4; ++j) {
                const int row = row0 + wrM + m * 16 + lg * 4 + j;
                const int col = col0 + wcN + n * 16 + lr;
                const long long idx = (long long)row * ldc + col;
                float v = acc[m][n][j] * scale;
                if constexpr (EPI == EPI_F32) {
                    Cf[idx] = v;
                } else if constexpr (EPI == EPI_BF16) {
                    Cb[idx] = f2bf(v);
                } else if constexpr (EPI == EPI_BIAS_RELU_BF16) {
                    v += bias[col];
                    v = v > 0.f ? v : 0.f;
                    Cb[idx] = f2bf(v);
                } else if constexpr (EPI == EPI_RESID_F32) {
                    Cf[idx] = v + R[idx];
                } else {
                    Cf[idx] = v + bias[col] + R[idx];
                }
            }
}

// ======================= 128x128 engine (r10) ==============================
template <int EPI, bool CSKIP, bool KLIM>
__global__ __launch_bounds__(256, 2) void gemm128(
    const unsigned short* __restrict__ A,
    const unsigned short* __restrict__ Bm,
    void* __restrict__ Cout,
    const float* __restrict__ bias,
    const float* __restrict__ resid,
    int M, int N, int K, int lda, int ldb, float scale,
    long long batA, long long batB, long long batC, long long batR)
{
    __shared__ __align__(16) unsigned char lds[65536];

    const int gx = gridDim.x;
    const int nwg = gx * gridDim.y;
    int bl = blockIdx.y * gx + blockIdx.x;
    bl = (bl & 7) * (nwg >> 3) + (bl >> 3);
    const int bx = bl % gx, by = bl / gx;

    const int row0 = by * 128, col0 = bx * 128;
    if (CSKIP && col0 > row0) return;

    const int bz = blockIdx.z;
    const unsigned short* Ab = A + (long long)bz * batA + (long long)row0 * lda;
    const unsigned short* Bb = Bm + (long long)bz * batB + (long long)col0 * ldb;

    const int tid = threadIdx.x, lane = tid & 63, wid = tid >> 6;
    const int wrM = (wid >> 1) * 64;
    const int wcN = (wid & 1) * 64;
    const int lr = lane & 15, lg = lane >> 4;

    int Keff = K;
    if (KLIM) { int kl = row0 + 128; Keff = kl < K ? kl : K; }
    const int nkt = Keff >> 6;

    const int c0 = wid * 128 + lane;
    const int crow = c0 >> 2;
    const int sg = (c0 & 3) ^ ((c0 >> 3) & 3);
    const unsigned short* gA0 = Ab + (long long)crow * lda + sg * 8;
    const unsigned short* gA1 = gA0 + 16ll * lda;
    const unsigned short* gB0 = Bb + (long long)crow * ldb + sg * 8;
    const unsigned short* gB1 = gB0 + 16ll * ldb;

    const int sw = (lg ^ ((lr >> 1) & 3)) << 4;
    const int aoff = (wrM + lr) * 64 + sw;
    const int boff = 8192 + (wcN + lr) * 64 + sw;

    f32x4_t acc[4][4];
#pragma unroll
    for (int m = 0; m < 4; ++m)
#pragma unroll
        for (int n = 0; n < 4; ++n)
            acc[m][n] = (f32x4_t){0.f, 0.f, 0.f, 0.f};

    auto stage2 = [&](int b, int kk, int ktn) {
        const int ke = ktn * 64 + kk * 32;
        unsigned char* uA = lds + b * 32768 + kk * 16384 + wid * 2048;
        unsigned char* uB = uA + 8192;
        gload16(gA0 + ke, uA);
        gload16(gA1 + ke, uA + 1024);
        gload16(gB0 + ke, uB);
        gload16(gB1 + ke, uB + 1024);
    };

    bf16x8_t af[4], bv[4];
    auto dsAB = [&](int b, int kk) {
        const unsigned char* u = lds + b * 32768 + kk * 16384;
#pragma unroll
        for (int m = 0; m < 4; ++m)
            af[m] = *(const bf16x8_t*)(u + aoff + m * 1024);
#pragma unroll
        for (int n = 0; n < 4; ++n)
            bv[n] = *(const bf16x8_t*)(u + boff + n * 1024);
    };
    auto mf16 = [&]() {
        __builtin_amdgcn_s_setprio(1);
#pragma unroll
        for (int m = 0; m < 4; ++m)
#pragma unroll
            for (int n = 0; n < 4; ++n)
                acc[m][n] = __builtin_amdgcn_mfma_f32_16x16x32_bf16(
                    af[m], bv[n], acc[m][n], 0, 0, 0);
        __builtin_amdgcn_s_setprio(0);
    };

    stage2(0, 0, 0); stage2(0, 1, 0);
    VM4_BAR();

    int kt = 0;
    for (; kt < nkt - 1; ++kt) {
        const int buf = kt & 1, nb = buf ^ 1;
        dsAB(buf, 0);
        stage2(nb, 0, kt + 1);
        BAR_LGKM(); SB0();
        mf16(); SB0();
        VM4_BAR();
        dsAB(buf, 1);
        stage2(nb, 1, kt + 1);
        BAR_LGKM(); SB0();
        mf16(); SB0();
        VM4_BAR();
    }
    {
        const int buf = kt & 1;
        dsAB(buf, 0);
        BAR_LGKM(); SB0();
        mf16(); SB0();
        VM0_BAR();
        dsAB(buf, 1);
        BAR_LGKM(); SB0();
        mf16(); SB0();
    }

    const int ldc = N;
    float* Cf = (float*)Cout + (long long)bz * batC;
    unsigned short* Cb = (unsigned short*)Cout + (long long)bz * batC;
    const float* R = nullptr;
    if constexpr (EPI == EPI_RESID_F32 || EPI == EPI_BIAS_RESID_F32)
        R = resid + (long long)bz * batR;

#pragma unroll
    for (int m = 0; m < 4; ++m)
#pragma unroll
        for (int n = 0; n < 4; ++n)
#pragma unroll
            for (int j = 0; j < 4; ++j) {
                const int row = row0 + wrM + m * 16 + lg * 4 + j;
                const int col = col0 + wcN + n * 16 + lr;
                const long long idx = (long long)row * ldc + col;
                float v = acc[m][n][j] * scale;
                if constexpr (EPI == EPI_F32) {
                    Cf[idx] = v;
                } else if constexpr (EPI == EPI_BF16) {
                    Cb[idx] = f2bf(v);
                } else if constexpr (EPI == EPI_BIAS_RELU_BF16) {
                    v += bias[col];
                    v = v > 0.f ? v : 0.f;
                    Cb[idx] = f2bf(v);
                } else if constexpr (EPI == EPI_RESID_F32) {
                    Cf[idx] = v + R[idx];
                } else {
                    Cf[idx] = v + bias[col] + R[idx];
                }
            }
}

// ================== pv: paired-KLIM 128x128 engine (r12) ===================
__global__ __launch_bounds__(256, 2) void pv_k(
    const unsigned short* __restrict__ Pm,   // [B][T][T] bf16, row zero-pad
    const unsigned short* __restrict__ vT,   // [C][B*T]
    float* __restrict__ xres,
    const float* __restrict__ x,
    int Tt, int Cc, int BT)
{
    __shared__ __align__(16) unsigned char lds[65536];

    const int gx = gridDim.x;                // 8
    const int nwg = gx * gridDim.y;          // 64
    int bl = blockIdx.y * gx + blockIdx.x;
    bl = (bl & 7) * (nwg >> 3) + (bl >> 3);
    const int bx = bl % gx, by = bl / gx;    // by = pair index 0..7
    const int bz = blockIdx.z;

    const int col0 = bx * 128;
    const int tid = threadIdx.x, lane = tid & 63, wid = tid >> 6;
    const int wrM = (wid >> 1) * 64;
    const int wcN = (wid & 1) * 64;
    const int lr = lane & 15, lg = lane >> 4;

    const int c0 = wid * 128 + lane;
    const int crow = c0 >> 2;
    const int sg = (c0 & 3) ^ ((c0 >> 3) & 3);

    const int lda = Tt, ldb = BT, ldc = Cc;
    const unsigned short* Bb = vT + (long long)bz * Tt + (long long)col0 * ldb;
    const unsigned short* gB0 = Bb + (long long)crow * ldb + sg * 8;
    const unsigned short* gB1 = gB0 + 16ll * ldb;

    const int sw = (lg ^ ((lr >> 1) & 3)) << 4;
    const int aoff = (wrM + lr) * 64 + sw;
    const int boff = 8192 + (wcN + lr) * 64 + sw;

    bf16x8_t af[4], bv[4];
    auto dsAB = [&](int b, int kk) {
        const unsigned char* u = lds + b * 32768 + kk * 16384;
#pragma unroll
        for (int m = 0; m < 4; ++m)
            af[m] = *(const bf16x8_t*)(u + aoff + m * 1024);
#pragma unroll
        for (int n = 0; n < 4; ++n)
            bv[n] = *(const bf16x8_t*)(u + boff + n * 1024);
    };

    float* Cf = xres + (long long)bz * Tt * Cc;
    const float* R = x + (long long)bz * Tt * Cc;

    for (int pass = 0; pass < 2; ++pass) {
        const int by_eff = pass ? (15 - by) : by;
        const int row0 = by_eff * 128;
        const int nkt = (row0 + 128) >> 6;

        const unsigned short* Ab = Pm + (long long)bz * Tt * Tt + (long long)row0 * lda;
        const unsigned short* gA0 = Ab + (long long)crow * lda + sg * 8;
        const unsigned short* gA1 = gA0 + 16ll * lda;

        auto stage2 = [&](int b, int kk, int ktn) {
            const int ke = ktn * 64 + kk * 32;
            unsigned char* uA = lds + b * 32768 + kk * 16384 + wid * 2048;
            unsigned char* uB = uA + 8192;
            gload16(gA0 + ke, uA);
            gload16(gA1 + ke, uA + 1024);
            gload16(gB0 + ke, uB);
            gload16(gB1 + ke, uB + 1024);
        };

        f32x4_t acc[4][4];
#pragma unroll
        for (int m = 0; m < 4; ++m)
#pragma unroll
            for (int n = 0; n < 4; ++n)
                acc[m][n] = (f32x4_t){0.f, 0.f, 0.f, 0.f};

        auto mf16 = [&]() {
            __builtin_amdgcn_s_setprio(1);
#pragma unroll
            for (int m = 0; m < 4; ++m)
#pragma unroll
                for (int n = 0; n < 4; ++n)
                    acc[m][n] = __builtin_amdgcn_mfma_f32_16x16x32_bf16(
                        af[m], bv[n], acc[m][n], 0, 0, 0);
            __builtin_amdgcn_s_setprio(0);
        };

        if (pass) BAR();   // all waves done reading LDS from pass 0
        stage2(0, 0, 0); stage2(0, 1, 0);
        VM4_BAR();

        int kt = 0;
        for (; kt < nkt - 1; ++kt) {
            const int buf = kt & 1, nb = buf ^ 1;
            dsAB(buf, 0);
            stage2(nb, 0, kt + 1);
            BAR_LGKM(); SB0();
            mf16(); SB0();
            VM4_BAR();
            dsAB(buf, 1);
            stage2(nb, 1, kt + 1);
            BAR_LGKM(); SB0();
            mf16(); SB0();
            VM4_BAR();
        }
        {
            const int buf = kt & 1;
            dsAB(buf, 0);
            BAR_LGKM(); SB0();
            mf16(); SB0();
            VM0_BAR();
            dsAB(buf, 1);
            BAR_LGKM(); SB0();
            mf16(); SB0();
        }

#pragma unroll
        for (int m = 0; m < 4; ++m)
#pragma unroll
            for (int n = 0; n < 4; ++n)
#pragma unroll
                for (int j = 0; j < 4; ++j) {
                    const int row = row0 + wrM + m * 16 + lg * 4 + j;
                    const int col = col0 + wcN + n * 16 + lr;
                    const long long idx = (long long)row * ldc + col;
                    Cf[idx] = acc[m][n][j] + R[idx];
                }
    }
}

// ------------- transpose + fp32->bf16 convert: in [R][Cc] -> out [Cc][R] ----
__global__ __launch_bounds__(256) void tconv_k(
    const float* __restrict__ in, unsigned short* __restrict__ out,
    int R, int Cc)
{
    __shared__ float t[64][65];
    const int r0 = blockIdx.y * 64, c0 = blockIdx.x * 64;
    const int tid = threadIdx.x;
    const int a = tid >> 4;
    const int b = tid & 15;
#pragma unroll
    for (int i = 0; i < 4; ++i) {
        const int row = a + i * 16;
        float4 v = *(const float4*)(in + (long long)(r0 + row) * Cc + c0 + b * 4);
        t[row][b * 4 + 0] = v.x; t[row][b * 4 + 1] = v.y;
        t[row][b * 4 + 2] = v.z; t[row][b * 4 + 3] = v.w;
    }
    __syncthreads();
#pragma unroll
    for (int i = 0; i < 4; ++i) {
        const int oc = a + i * 16;
        ushort4 o;
        o.x = f2bf(t[b * 4 + 0][oc]);
        o.y = f2bf(t[b * 4 + 1][oc]);
        o.z = f2bf(t[b * 4 + 2][oc]);
        o.w = f2bf(t[b * 4 + 3][oc]);
        *(ushort4*)(out + (long long)(c0 + oc) * R + r0 + b * 4) = o;
    }
}

// ------ bf16 transpose of the v-slice: qkv[8192][3072]@col2048 -> vT[1024][8192]
__global__ __launch_bounds__(256) void vtrans_k(
    const unsigned short* __restrict__ in, unsigned short* __restrict__ out)
{
    __shared__ unsigned short t[64][72];
    const int r0 = blockIdx.x * 64;
    const int c0 = blockIdx.y * 64;
    const int tid = threadIdx.x;
#pragma unroll
    for (int i = 0; i < 2; ++i) {
        const int ch = tid * 2 + i;
        const int row = ch >> 3, cs = ch & 7;
        int4 v = *(const int4*)(in + (long long)(r0 + row) * 3072 + 2048 + c0 + cs * 8);
        *(int4*)&t[row][cs * 8] = v;
    }
    __syncthreads();
#pragma unroll
    for (int i = 0; i < 2; ++i) {
        const int w = tid * 2 + i;
        const int oc = w >> 3, orc = w & 7;
        unsigned short tmp[8];
#pragma unroll
        for (int j = 0; j < 8; ++j) tmp[j] = t[orc * 8 + j][oc];
        *(int4*)(out + (long long)(c0 + oc) * 8192 + r0 + orc * 8) = *(const int4*)tmp;
    }
}

// ---------------- LayerNorm: one wave per 1024-elem row ---------------------
__global__ __launch_bounds__(256) void ln_k(
    const float* __restrict__ x, const float* __restrict__ g,
    const float* __restrict__ be, unsigned short* __restrict__ out)
{
    const int wv = threadIdx.x >> 6, lane = threadIdx.x & 63;
    const long long row = blockIdx.x * 4 + wv;
    const float* xr = x + row * 1024;
    float4 v[4];
    float s = 0.f, q = 0.f;
#pragma unroll
    for (int j = 0; j < 4; ++j) {
        v[j] = *(const float4*)(xr + j * 256 + lane * 4);
        s += v[j].x + v[j].y + v[j].z + v[j].w;
        q += v[j].x * v[j].x + v[j].y * v[j].y + v[j].z * v[j].z + v[j].w * v[j].w;
    }
#pragma unroll
    for (int off = 32; off > 0; off >>= 1) {
        s += __shfl_xor(s, off);
        q += __shfl_xor(q, off);
    }
    const float mean = s * (1.0f / 1024.0f);
    const float var  = q * (1.0f / 1024.0f) - mean * mean;
    const float rstd = rsqrtf(var + 1e-5f);
#pragma unroll
    for (int j = 0; j < 4; ++j) {
        float4 gv = *(const float4*)(g + j * 256 + lane * 4);
        float4 bv = *(const float4*)(be + j * 256 + lane * 4);
        ushort4 o;
        o.x = f2bf((v[j].x - mean) * rstd * gv.x + bv.x);
        o.y = f2bf((v[j].y - mean) * rstd * gv.y + bv.y);
        o.z = f2bf((v[j].z - mean) * rstd * gv.z + bv.z);
        o.w = f2bf((v[j].w - mean) * rstd * gv.w + bv.w);
        *(ushort4*)(out + row * 1024 + j * 256 + lane * 4) = o;
    }
}

// ------- causal row softmax: warp-per-row, register-resident ---------------
// Row t: valid n=t+1, zero-pad to lim=128-multiple.  Each lane holds up to
// 32 f32 (4 chunks of int4); wave-uniform chunk guards keep static indexing.
__global__ __launch_bounds__(256) void softmax_k(
    const unsigned short* __restrict__ S, unsigned short* __restrict__ P, int T)
{
    const int wv = threadIdx.x >> 6, lane = threadIdx.x & 63;
    const int t = blockIdx.x * 4 + wv;
    const long long base = ((long long)blockIdx.y * T + t) * (long long)T;
    const unsigned short* srow = S + base;
    unsigned short* prow = P + base;
    const int n = t + 1;
    const int lim = ((t >> 7) + 1) << 7;       // 128-multiple <= T
    const int nch = (lim + 511) >> 9;          // chunks of 512 elems

    float v[4][8];
    float mx = -3.0e38f;
#pragma unroll
    for (int j = 0; j < 4; ++j) {
        if (j < nch) {
            const int e0 = (j * 64 + lane) * 8;
            int4 r = *(const int4*)(srow + e0);
            const unsigned short* u = (const unsigned short*)&r;
#pragma unroll
            for (int i = 0; i < 8; ++i) {
                float f = bf2f(u[i]);
                v[j][i] = f;
                if (e0 + i < n) mx = fmaxf(mx, f);
            }
        }
    }
#pragma unroll
    for (int off = 32; off > 0; off >>= 1) mx = fmaxf(mx, __shfl_xor(mx, off));

    float sum = 0.f;
#pragma unroll
    for (int j = 0; j < 4; ++j) {
        if (j < nch) {
            const int e0 = (j * 64 + lane) * 8;
#pragma unroll
            for (int i = 0; i < 8; ++i) {
                float e = (e0 + i < n) ? __expf(v[j][i] - mx) : 0.f;
                v[j][i] = e;
                sum += e;
            }
        }
    }
#pragma unroll
    for (int off = 32; off > 0; off >>= 1) sum += __shfl_xor(sum, off);
    const float inv = 1.0f / sum;

#pragma unroll
    for (int j = 0; j < 4; ++j) {
        if (j < nch) {
            const int e0 = (j * 64 + lane) * 8;
            unsigned short o[8];
#pragma unroll
            for (int i = 0; i < 8; ++i) o[i] = f2bf(v[j][i] * inv);
            *(int4*)(prow + e0) = *(const int4*)o;
        }
    }
}

// ---------------------------------------------------------------------------
extern "C" void kernel_launch(void* const* d_in, const int* in_sizes, int n_in,
                              void* d_out, int out_size, void* d_ws, size_t ws_size,
                              hipStream_t stream)
{
    const int B = 4, T = 2048, C = 1024, F = 4096;
    const float* x   = (const float*)d_in[0];
    const float* Wk  = (const float*)d_in[1];
    const float* Wq  = (const float*)d_in[2];
    const float* Wv  = (const float*)d_in[3];
    const float* W1  = (const float*)d_in[4];
    const float* b1  = (const float*)d_in[5];
    const float* W2  = (const float*)d_in[6];
    const float* b2  = (const float*)d_in[7];
    const float* g1  = (const float*)d_in[8];
    const float* be1 = (const float*)d_in[9];
    const float* g2  = (const float*)d_in[10];
    const float* be2 = (const float*)d_in[11];

    char* ws = (char*)d_ws;
    const size_t MB = 1ull << 20;
    unsigned short* h     = (unsigned short*)(ws + 0);         // 16 MiB
    unsigned short* qkv   = (unsigned short*)(ws + 16 * MB);   // 48 MiB [8192][3072]
    unsigned short* vT    = (unsigned short*)(ws + 64 * MB);   // 16 MiB [1024][8192]
    float*          xres  = (float*)(ws + 80 * MB);            // 32 MiB
    unsigned short* S     = (unsigned short*)(ws + 112 * MB);  // 32 MiB bf16 [B][T][T]
    unsigned short* P     = (unsigned short*)(ws + 144 * MB);  // 32 MiB
    unsigned short* ff1   = (unsigned short*)(ws + 112 * MB);  // 64 MiB (aliases S+P)
    unsigned short* wqkvT = (unsigned short*)(ws + 176 * MB);  // 6 MiB [3C][C]
    unsigned short* w1T   = (unsigned short*)(ws + 182 * MB);  // 8 MiB [F][C]
    unsigned short* w2T   = (unsigned short*)(ws + 190 * MB);  // 8 MiB [C][F]

    // transposed weight converts (q,k,v fused into wqkvT)
    tconv_k<<<dim3(16, 16), 256, 0, stream>>>(Wq, wqkvT, C, C);
    tconv_k<<<dim3(16, 16), 256, 0, stream>>>(Wk, wqkvT + C * C, C, C);
    tconv_k<<<dim3(16, 16), 256, 0, stream>>>(Wv, wqkvT + 2 * C * C, C, C);
    tconv_k<<<dim3(64, 16), 256, 0, stream>>>(W1, w1T, C, F);
    tconv_k<<<dim3(16, 64), 256, 0, stream>>>(W2, w2T, F, C);

    // LN1
    ln_k<<<dim3(B * T / 4), 256, 0, stream>>>(x, g1, be1, h);

    // [q|k|v] = h @ [Wq|Wk|Wv]   (M=8192, N=3072, K=1024) -> 384 blocks @256²
    dim3 gqkv(3 * C / 256, (B * T) / 256, 1);
    gemm256<EPI_BF16, false, false><<<gqkv, 512, 0, stream>>>(
        h, wqkvT, qkv, nullptr, nullptr, B * T, 3 * C, C, C, C, 1.0f, 0, 0, 0, 0);

    // vT = transpose of v-slice
    vtrans_k<<<dim3(B * T / 64, C / 64), 256, 0, stream>>>(qkv, vT);

    // S = q @ k^T / 32 (bf16; causal tiles only) -> 144 alive @256²
    dim3 gsc(T / 256, T / 256, B);
    gemm256<EPI_BF16, true, false><<<gsc, 512, 0, stream>>>(
        qkv, qkv + C, S, nullptr, nullptr, T, T, C, 3 * C, 3 * C, 0.03125f,
        (long long)T * 3 * C, (long long)T * 3 * C, (long long)T * T, 0);

    // P = causal softmax(S), warp-per-row
    softmax_k<<<dim3(T / 4, B), 256, 0, stream>>>(S, P, T);

    // xres = x + P @ v : paired-KLIM engine, 256 balanced blocks
    pv_k<<<dim3(C / 128, 8, B), 256, 0, stream>>>(
        P, vT, xres, x, T, C, B * T);

    // LN2
    ln_k<<<dim3(B * T / 4), 256, 0, stream>>>(xres, g2, be2, h);

    // ff1 = relu(h @ W1 + b1)   (M=8192, N=4096, K=1024) -> 512 blocks @256²
    dim3 gf1(F / 256, (B * T) / 256, 1);
    gemm256<EPI_BIAS_RELU_BF16, false, false><<<gf1, 512, 0, stream>>>(
        h, w1T, ff1, b1, nullptr, B * T, F, C, C, C, 1.0f, 0, 0, 0, 0);

    // out = xres + ff1 @ W2 + b2   (M=8192, N=1024, K=4096) -> 512 blocks @128²
    dim3 gf2(C / 128, (B * T) / 128, 1);
    gemm128<EPI_BIAS_RESID_F32, false, false><<<gf2, 256, 0, stream>>>(
        ff1, w2T, (float*)d_out, b2, xres, B * T, C, F, F, F, 1.0f, 0, 0, 0, 0);
}

// Round 14
// 343.639 us; speedup vs baseline: 1.0843x; 1.0421x over previous
//
#include <hip/hip_runtime.h>
#include <hip/hip_bf16.h>

// ---------------------------------------------------------------------------
// Transformer block forward (B=4, T=2048, C=1024, F=4096).
// Engines:
//  - gemm256 (r9): 256x256, 512 thr, 4 phases/K-tile alt-quadrant, counted
//    vmcnt (~890 TF @K=1024).  Used for qk / ff1.
//  - gemm128 (r10): 128x128, 256 thr, 64 KiB LDS -> 2 blocks/CU.  ff2.
//  - pv_k (r12): gemm128 body, complementary-pair KLIM (balanced).
//  - sc_vt_k (r14): scores (causal 256² tiles) + vT tiles FUSED in one
//    launch — dead causal blocks remap to vT = Wv^T @ h^T tiles, packing
//    what was 1 partial round + a vtrans kernel into ~1.06 uniform rounds.
// Softmax: warp-per-row register-resident.
// All GEMMs: T2 (row>>1)&3 swizzle (bank-conflict 0), T5 setprio, T1
// bijective XCD swizzle, global_load_lds width-16 staging.
// ---------------------------------------------------------------------------

typedef __bf16 bf16x8_t __attribute__((ext_vector_type(8)));
typedef float f32x4_t __attribute__((ext_vector_type(4)));

__device__ __forceinline__ unsigned short f2bf(float f) {
    unsigned int u = __float_as_uint(f);
    u += 0x7fffu + ((u >> 16) & 1u);   // round-to-nearest-even
    return (unsigned short)(u >> 16);
}
__device__ __forceinline__ float bf2f(unsigned short u) {
    return __uint_as_float((unsigned int)u << 16);
}

__device__ __forceinline__ void gload16(const void* g, void* lds) {
    __builtin_amdgcn_global_load_lds(
        (const __attribute__((address_space(1))) unsigned int*)g,
        (__attribute__((address_space(3))) unsigned int*)lds, 16, 0, 0);
}

#define SB0() __builtin_amdgcn_sched_barrier(0)
#define BAR_LGKM() asm volatile("s_barrier\ns_waitcnt lgkmcnt(0)" ::: "memory")
#define BAR() asm volatile("s_barrier" ::: "memory")
#define VM4_BAR() asm volatile("s_waitcnt vmcnt(4)\ns_barrier" ::: "memory")
#define VM0_BAR() asm volatile("s_waitcnt vmcnt(0)\ns_barrier" ::: "memory")

enum { EPI_F32 = 0, EPI_BF16 = 1, EPI_BIAS_RELU_BF16 = 2, EPI_RESID_F32 = 3,
       EPI_BIAS_RESID_F32 = 4 };

// ======================= 256x256 engine (r9) ===============================
template <int EPI, bool CSKIP, bool KLIM>
__global__ __launch_bounds__(512, 2) void gemm256(
    const unsigned short* __restrict__ A,
    const unsigned short* __restrict__ Bm,
    void* __restrict__ Cout,
    const float* __restrict__ bias,
    const float* __restrict__ resid,
    int M, int N, int K, int lda, int ldb, float scale,
    long long batA, long long batB, long long batC, long long batR)
{
    __shared__ __align__(16) unsigned char lds[131072];

    const int gx = gridDim.x;
    const int nwg = gx * gridDim.y;
    int bl = blockIdx.y * gx + blockIdx.x;
    bl = (bl & 7) * (nwg >> 3) + (bl >> 3);
    const int bx = bl % gx, by = bl / gx;

    const int row0 = by * 256, col0 = bx * 256;
    if (CSKIP && col0 > row0) return;

    const int bz = blockIdx.z;
    const unsigned short* Ab = A + (long long)bz * batA + (long long)row0 * lda;
    const unsigned short* Bb = Bm + (long long)bz * batB + (long long)col0 * ldb;

    const int tid = threadIdx.x, lane = tid & 63, wid = tid >> 6;
    const int wrM = (wid >> 2) * 128;
    const int wcN = (wid & 3) * 64;
    const int lr = lane & 15, lg = lane >> 4;

    int Keff = K;
    if (KLIM) { int kl = row0 + 256; Keff = kl < K ? kl : K; }
    const int nkt = Keff >> 6;

    const int c0 = wid * 128 + lane;
    const int crow = c0 >> 2;
    const int sg = (c0 & 3) ^ ((c0 >> 3) & 3);
    const unsigned short* gA0 = Ab + (long long)crow * lda + sg * 8;
    const unsigned short* gA1 = gA0 + 16ll * lda;
    const unsigned short* gB0 = Bb + (long long)crow * ldb + sg * 8;
    const unsigned short* gB1 = gB0 + 16ll * ldb;

    const int sw = (lg ^ ((lr >> 1) & 3)) << 4;
    const int aoff = (wrM + lr) * 64 + sw;
    const int boff = 16384 + (wcN + lr) * 64 + sw;

    f32x4_t acc[8][4];
#pragma unroll
    for (int m = 0; m < 8; ++m)
#pragma unroll
        for (int n = 0; n < 4; ++n)
            acc[m][n] = (f32x4_t){0.f, 0.f, 0.f, 0.f};

    auto stageR = [&](int b, int r, int ktn) {
        const int kk = r >> 1, op = r & 1;
        const int ke = ktn * 64 + kk * 32;
        unsigned char* d = lds + b * 65536 + kk * 32768 + op * 16384 + wid * 2048;
        const unsigned short* g0 = (op ? gB0 : gA0) + ke;
        const unsigned short* g1 = (op ? gB1 : gA1) + ke;
        gload16(g0, d);
        gload16(g1, d + 1024);
    };

    bf16x8_t af[4], bv[4];
    auto dsA4 = [&](int b, int kk, int mq) {
        const unsigned char* u = lds + b * 65536 + kk * 32768;
#pragma unroll
        for (int j = 0; j < 4; ++j)
            af[j] = *(const bf16x8_t*)(u + aoff + (mq * 4 + j) * 1024);
    };
    auto dsB4 = [&](int b, int kk) {
        const unsigned char* u = lds + b * 65536 + kk * 32768;
#pragma unroll
        for (int n = 0; n < 4; ++n)
            bv[n] = *(const bf16x8_t*)(u + boff + n * 1024);
    };
    auto mf16 = [&](int mq) {
        __builtin_amdgcn_s_setprio(1);
#pragma unroll
        for (int j = 0; j < 4; ++j)
#pragma unroll
            for (int n = 0; n < 4; ++n)
                acc[mq * 4 + j][n] = __builtin_amdgcn_mfma_f32_16x16x32_bf16(
                    af[j], bv[n], acc[mq * 4 + j][n], 0, 0, 0);
        __builtin_amdgcn_s_setprio(0);
    };

    stageR(0, 0, 0); stageR(0, 1, 0); stageR(0, 2, 0); stageR(0, 3, 0);
    VM4_BAR();

    int kt = 0;
    for (; kt < nkt - 1; ++kt) {
        const int buf = kt & 1, nb = buf ^ 1;
        dsA4(buf, 0, 0); dsB4(buf, 0);
        stageR(nb, 0, kt + 1);
        BAR_LGKM(); SB0();
        mf16(0); SB0();
        BAR();
        dsA4(buf, 0, 1);
        stageR(nb, 1, kt + 1);
        BAR_LGKM(); SB0();
        mf16(1); SB0();
        VM4_BAR();
        dsA4(buf, 1, 0); dsB4(buf, 1);
        stageR(nb, 2, kt + 1);
        BAR_LGKM(); SB0();
        mf16(0); SB0();
        BAR();
        dsA4(buf, 1, 1);
        stageR(nb, 3, kt + 1);
        BAR_LGKM(); SB0();
        mf16(1); SB0();
        VM4_BAR();
    }
    {
        const int buf = kt & 1;
        dsA4(buf, 0, 0); dsB4(buf, 0);
        BAR_LGKM(); SB0();
        mf16(0); SB0();
        BAR();
        dsA4(buf, 0, 1);
        BAR_LGKM(); SB0();
        mf16(1); SB0();
        VM0_BAR();
        dsA4(buf, 1, 0); dsB4(buf, 1);
        BAR_LGKM(); SB0();
        mf16(0); SB0();
        BAR();
        dsA4(buf, 1, 1);
        BAR_LGKM(); SB0();
        mf16(1); SB0();
    }

    const int ldc = N;
    float* Cf = (float*)Cout + (long long)bz * batC;
    unsigned short* Cb = (unsigned short*)Cout + (long long)bz * batC;
    const float* R = nullptr;
    if constexpr (EPI == EPI_RESID_F32 || EPI == EPI_BIAS_RESID_F32)
        R = resid + (long long)bz * batR;

#pragma unroll
    for (int m = 0; m < 8; ++m)
#pragma unroll
        for (int n = 0; n < 4; ++n)
#pragma unroll
            for (int j = 0; j < 4; ++j) {
                const int row = row0 + wrM + m * 16 + lg * 4 + j;
                const int col = col0 + wcN + n * 16 + lr;
                const long long idx = (long long)row * ldc + col;
                float v = acc[m][n][j] * scale;
                if constexpr (EPI == EPI_F32) {
                    Cf[idx] = v;
                } else if constexpr (EPI == EPI_BF16) {
                    Cb[idx] = f2bf(v);
                } else if constexpr (EPI == EPI_BIAS_RELU_BF16) {
                    v += bias[col];
                    v = v > 0.f ? v : 0.f;
                    Cb[idx] = f2bf(v);
                } else if constexpr (EPI == EPI_RESID_F32) {
                    Cf[idx] = v + R[idx];
                } else {
                    Cf[idx] = v + bias[col] + R[idx];
                }
            }
}

// ============== fused scores + vT kernel (r14) =============================
// grid (8, 9, 4), 512 thr.  Alive causal blocks (by<8, bx<=by): S tile
// (q@k^T/32, bf16).  Dead blocks remap to one of 128 vT tiles
// (vT = Wv^T @ h^T, M=1024, N=8192, K=1024).  All jobs: K=1024 (nkt=16).
__global__ __launch_bounds__(512, 2) void sc_vt_k(
    const unsigned short* __restrict__ qk,   // [8192][2048]  (q|k)
    const unsigned short* __restrict__ wvT,  // [1024][1024]
    const unsigned short* __restrict__ h,    // [8192][1024]
    unsigned short* __restrict__ Sm,         // [4][2048][2048]
    unsigned short* __restrict__ vTo)        // [1024][8192]
{
    __shared__ __align__(16) unsigned char lds[131072];

    int bl = blockIdx.y * 8 + blockIdx.x;    // nwg = 72, 72%8==0
    bl = (bl & 7) * 9 + (bl >> 3);
    const int bx = bl & 7, by = bl >> 3;     // bx in [0,8), by in [0,9)
    const int z = blockIdx.z;

    const unsigned short* Ab;
    const unsigned short* Bb;
    unsigned short* Cb;
    int lda, ldb, ldc, row0, col0;
    float scale;

    if (by < 8 && bx <= by) {
        // scores tile
        row0 = by * 256; col0 = bx * 256;
        lda = 2048; ldb = 2048; ldc = 2048;
        Ab = qk + ((long long)z * 2048 + row0) * 2048;          // q rows
        Bb = qk + ((long long)z * 2048 + col0) * 2048 + 1024;   // k rows
        Cb = Sm + (long long)z * 2048 * 2048;
        scale = 0.03125f;
    } else {
        int d;
        if (by < 8) d = z * 28 + ((bx * (bx - 1)) >> 1) + by;   // bx > by
        else        d = 112 + z * 8 + bx;                       // by == 8
        if (d >= 128) return;
        const int rt = d >> 5, ct = d & 31;
        row0 = rt * 256; col0 = ct * 256;
        lda = 1024; ldb = 1024; ldc = 8192;
        Ab = wvT + (long long)row0 * 1024;
        Bb = h + (long long)col0 * 1024;
        Cb = vTo;
        scale = 1.0f;
    }
    Ab += 0; Bb += 0;

    const int tid = threadIdx.x, lane = tid & 63, wid = tid >> 6;
    const int wrM = (wid >> 2) * 128;
    const int wcN = (wid & 3) * 64;
    const int lr = lane & 15, lg = lane >> 4;
    const int nkt = 16;                       // K = 1024 for both jobs

    const int c0 = wid * 128 + lane;
    const int crow = c0 >> 2;
    const int sg = (c0 & 3) ^ ((c0 >> 3) & 3);
    const unsigned short* gA0 = Ab + (long long)crow * lda + sg * 8;
    const unsigned short* gA1 = gA0 + 16ll * lda;
    const unsigned short* gB0 = Bb + (long long)crow * ldb + sg * 8;
    const unsigned short* gB1 = gB0 + 16ll * ldb;

    const int sw = (lg ^ ((lr >> 1) & 3)) << 4;
    const int aoff = (wrM + lr) * 64 + sw;
    const int boff = 16384 + (wcN + lr) * 64 + sw;

    f32x4_t acc[8][4];
#pragma unroll
    for (int m = 0; m < 8; ++m)
#pragma unroll
        for (int n = 0; n < 4; ++n)
            acc[m][n] = (f32x4_t){0.f, 0.f, 0.f, 0.f};

    auto stageR = [&](int b, int r, int ktn) {
        const int kk = r >> 1, op = r & 1;
        const int ke = ktn * 64 + kk * 32;
        unsigned char* d = lds + b * 65536 + kk * 32768 + op * 16384 + wid * 2048;
        const unsigned short* g0 = (op ? gB0 : gA0) + ke;
        const unsigned short* g1 = (op ? gB1 : gA1) + ke;
        gload16(g0, d);
        gload16(g1, d + 1024);
    };

    bf16x8_t af[4], bv[4];
    auto dsA4 = [&](int b, int kk, int mq) {
        const unsigned char* u = lds + b * 65536 + kk * 32768;
#pragma unroll
        for (int j = 0; j < 4; ++j)
            af[j] = *(const bf16x8_t*)(u + aoff + (mq * 4 + j) * 1024);
    };
    auto dsB4 = [&](int b, int kk) {
        const unsigned char* u = lds + b * 65536 + kk * 32768;
#pragma unroll
        for (int n = 0; n < 4; ++n)
            bv[n] = *(const bf16x8_t*)(u + boff + n * 1024);
    };
    auto mf16 = [&](int mq) {
        __builtin_amdgcn_s_setprio(1);
#pragma unroll
        for (int j = 0; j < 4; ++j)
#pragma unroll
            for (int n = 0; n < 4; ++n)
                acc[mq * 4 + j][n] = __builtin_amdgcn_mfma_f32_16x16x32_bf16(
                    af[j], bv[n], acc[mq * 4 + j][n], 0, 0, 0);
        __builtin_amdgcn_s_setprio(0);
    };

    stageR(0, 0, 0); stageR(0, 1, 0); stageR(0, 2, 0); stageR(0, 3, 0);
    VM4_BAR();

    int kt = 0;
    for (; kt < nkt - 1; ++kt) {
        const int buf = kt & 1, nb = buf ^ 1;
        dsA4(buf, 0, 0); dsB4(buf, 0);
        stageR(nb, 0, kt + 1);
        BAR_LGKM(); SB0();
        mf16(0); SB0();
        BAR();
        dsA4(buf, 0, 1);
        stageR(nb, 1, kt + 1);
        BAR_LGKM(); SB0();
        mf16(1); SB0();
        VM4_BAR();
        dsA4(buf, 1, 0); dsB4(buf, 1);
        stageR(nb, 2, kt + 1);
        BAR_LGKM(); SB0();
        mf16(0); SB0();
        BAR();
        dsA4(buf, 1, 1);
        stageR(nb, 3, kt + 1);
        BAR_LGKM(); SB0();
        mf16(1); SB0();
        VM4_BAR();
    }
    {
        const int buf = kt & 1;
        dsA4(buf, 0, 0); dsB4(buf, 0);
        BAR_LGKM(); SB0();
        mf16(0); SB0();
        BAR();
        dsA4(buf, 0, 1);
        BAR_LGKM(); SB0();
        mf16(1); SB0();
        VM0_BAR();
        dsA4(buf, 1, 0); dsB4(buf, 1);
        BAR_LGKM(); SB0();
        mf16(0); SB0();
        BAR();
        dsA4(buf, 1, 1);
        BAR_LGKM(); SB0();
        mf16(1); SB0();
    }

#pragma unroll
    for (int m = 0; m < 8; ++m)
#pragma unroll
        for (int n = 0; n < 4; ++n)
#pragma unroll
            for (int j = 0; j < 4; ++j) {
                const int row = row0 + wrM + m * 16 + lg * 4 + j;
                const int col = col0 + wcN + n * 16 + lr;
                Cb[(long long)row * ldc + col] = f2bf(acc[m][n][j] * scale);
            }
}

// ======================= 128x128 engine (r10) ==============================
template <int EPI, bool CSKIP, bool KLIM>
__global__ __launch_bounds__(256, 2) void gemm128(
    const unsigned short* __restrict__ A,
    const unsigned short* __restrict__ Bm,
    void* __restrict__ Cout,
    const float* __restrict__ bias,
    const float* __restrict__ resid,
    int M, int N, int K, int lda, int ldb, float scale,
    long long batA, long long batB, long long batC, long long batR)
{
    __shared__ __align__(16) unsigned char lds[65536];

    const int gx = gridDim.x;
    const int nwg = gx * gridDim.y;
    int bl = blockIdx.y * gx + blockIdx.x;
    bl = (bl & 7) * (nwg >> 3) + (bl >> 3);
    const int bx = bl % gx, by = bl / gx;

    const int row0 = by * 128, col0 = bx * 128;
    if (CSKIP && col0 > row0) return;

    const int bz = blockIdx.z;
    const unsigned short* Ab = A + (long long)bz * batA + (long long)row0 * lda;
    const unsigned short* Bb = Bm + (long long)bz * batB + (long long)col0 * ldb;

    const int tid = threadIdx.x, lane = tid & 63, wid = tid >> 6;
    const int wrM = (wid >> 1) * 64;
    const int wcN = (wid & 1) * 64;
    const int lr = lane & 15, lg = lane >> 4;

    int Keff = K;
    if (KLIM) { int kl = row0 + 128; Keff = kl < K ? kl : K; }
    const int nkt = Keff >> 6;

    const int c0 = wid * 128 + lane;
    const int crow = c0 >> 2;
    const int sg = (c0 & 3) ^ ((c0 >> 3) & 3);
    const unsigned short* gA0 = Ab + (long long)crow * lda + sg * 8;
    const unsigned short* gA1 = gA0 + 16ll * lda;
    const unsigned short* gB0 = Bb + (long long)crow * ldb + sg * 8;
    const unsigned short* gB1 = gB0 + 16ll * ldb;

    const int sw = (lg ^ ((lr >> 1) & 3)) << 4;
    const int aoff = (wrM + lr) * 64 + sw;
    const int boff = 8192 + (wcN + lr) * 64 + sw;

    f32x4_t acc[4][4];
#pragma unroll
    for (int m = 0; m < 4; ++m)
#pragma unroll
        for (int n = 0; n < 4; ++n)
            acc[m][n] = (f32x4_t){0.f, 0.f, 0.f, 0.f};

    auto stage2 = [&](int b, int kk, int ktn) {
        const int ke = ktn * 64 + kk * 32;
        unsigned char* uA = lds + b * 32768 + kk * 16384 + wid * 2048;
        unsigned char* uB = uA + 8192;
        gload16(gA0 + ke, uA);
        gload16(gA1 + ke, uA + 1024);
        gload16(gB0 + ke, uB);
        gload16(gB1 + ke, uB + 1024);
    };

    bf16x8_t af[4], bv[4];
    auto dsAB = [&](int b, int kk) {
        const unsigned char* u = lds + b * 32768 + kk * 16384;
#pragma unroll
        for (int m = 0; m < 4; ++m)
            af[m] = *(const bf16x8_t*)(u + aoff + m * 1024);
#pragma unroll
        for (int n = 0; n < 4; ++n)
            bv[n] = *(const bf16x8_t*)(u + boff + n * 1024);
    };
    auto mf16 = [&]() {
        __builtin_amdgcn_s_setprio(1);
#pragma unroll
        for (int m = 0; m < 4; ++m)
#pragma unroll
            for (int n = 0; n < 4; ++n)
                acc[m][n] = __builtin_amdgcn_mfma_f32_16x16x32_bf16(
                    af[m], bv[n], acc[m][n], 0, 0, 0);
        __builtin_amdgcn_s_setprio(0);
    };

    stage2(0, 0, 0); stage2(0, 1, 0);
    VM4_BAR();

    int kt = 0;
    for (; kt < nkt - 1; ++kt) {
        const int buf = kt & 1, nb = buf ^ 1;
        dsAB(buf, 0);
        stage2(nb, 0, kt + 1);
        BAR_LGKM(); SB0();
        mf16(); SB0();
        VM4_BAR();
        dsAB(buf, 1);
        stage2(nb, 1, kt + 1);
        BAR_LGKM(); SB0();
        mf16(); SB0();
        VM4_BAR();
    }
    {
        const int buf = kt & 1;
        dsAB(buf, 0);
        BAR_LGKM(); SB0();
        mf16(); SB0();
        VM0_BAR();
        dsAB(buf, 1);
        BAR_LGKM(); SB0();
        mf16(); SB0();
    }

    const int ldc = N;
    float* Cf = (float*)Cout + (long long)bz * batC;
    unsigned short* Cb = (unsigned short*)Cout + (long long)bz * batC;
    const float* R = nullptr;
    if constexpr (EPI == EPI_RESID_F32 || EPI == EPI_BIAS_RESID_F32)
        R = resid + (long long)bz * batR;

#pragma unroll
    for (int m = 0; m < 4; ++m)
#pragma unroll
        for (int n = 0; n < 4; ++n)
#pragma unroll
            for (int j = 0; j < 4; ++j) {
                const int row = row0 + wrM + m * 16 + lg * 4 + j;
                const int col = col0 + wcN + n * 16 + lr;
                const long long idx = (long long)row * ldc + col;
                float v = acc[m][n][j] * scale;
                if constexpr (EPI == EPI_F32) {
                    Cf[idx] = v;
                } else if constexpr (EPI == EPI_BF16) {
                    Cb[idx] = f2bf(v);
                } else if constexpr (EPI == EPI_BIAS_RELU_BF16) {
                    v += bias[col];
                    v = v > 0.f ? v : 0.f;
                    Cb[idx] = f2bf(v);
                } else if constexpr (EPI == EPI_RESID_F32) {
                    Cf[idx] = v + R[idx];
                } else {
                    Cf[idx] = v + bias[col] + R[idx];
                }
            }
}

// ================== pv: paired-KLIM 128x128 engine (r12) ===================
__global__ __launch_bounds__(256, 2) void pv_k(
    const unsigned short* __restrict__ Pm,   // [B][T][T] bf16, row zero-pad
    const unsigned short* __restrict__ vT,   // [C][B*T]
    float* __restrict__ xres,
    const float* __restrict__ x,
    int Tt, int Cc, int BT)
{
    __shared__ __align__(16) unsigned char lds[65536];

    const int gx = gridDim.x;                // 8
    const int nwg = gx * gridDim.y;          // 64
    int bl = blockIdx.y * gx + blockIdx.x;
    bl = (bl & 7) * (nwg >> 3) + (bl >> 3);
    const int bx = bl % gx, by = bl / gx;    // by = pair index 0..7
    const int bz = blockIdx.z;

    const int col0 = bx * 128;
    const int tid = threadIdx.x, lane = tid & 63, wid = tid >> 6;
    const int wrM = (wid >> 1) * 64;
    const int wcN = (wid & 1) * 64;
    const int lr = lane & 15, lg = lane >> 4;

    const int c0 = wid * 128 + lane;
    const int crow = c0 >> 2;
    const int sg = (c0 & 3) ^ ((c0 >> 3) & 3);

    const int lda = Tt, ldb = BT, ldc = Cc;
    const unsigned short* Bb = vT + (long long)bz * Tt + (long long)col0 * ldb;
    const unsigned short* gB0 = Bb + (long long)crow * ldb + sg * 8;
    const unsigned short* gB1 = gB0 + 16ll * ldb;

    const int sw = (lg ^ ((lr >> 1) & 3)) << 4;
    const int aoff = (wrM + lr) * 64 + sw;
    const int boff = 8192 + (wcN + lr) * 64 + sw;

    bf16x8_t af[4], bv[4];
    auto dsAB = [&](int b, int kk) {
        const unsigned char* u = lds + b * 32768 + kk * 16384;
#pragma unroll
        for (int m = 0; m < 4; ++m)
            af[m] = *(const bf16x8_t*)(u + aoff + m * 1024);
#pragma unroll
        for (int n = 0; n < 4; ++n)
            bv[n] = *(const bf16x8_t*)(u + boff + n * 1024);
    };

    float* Cf = xres + (long long)bz * Tt * Cc;
    const float* R = x + (long long)bz * Tt * Cc;

    for (int pass = 0; pass < 2; ++pass) {
        const int by_eff = pass ? (15 - by) : by;
        const int row0 = by_eff * 128;
        const int nkt = (row0 + 128) >> 6;

        const unsigned short* Ab = Pm + (long long)bz * Tt * Tt + (long long)row0 * lda;
        const unsigned short* gA0 = Ab + (long long)crow * lda + sg * 8;
        const unsigned short* gA1 = gA0 + 16ll * lda;

        auto stage2 = [&](int b, int kk, int ktn) {
            const int ke = ktn * 64 + kk * 32;
            unsigned char* uA = lds + b * 32768 + kk * 16384 + wid * 2048;
            unsigned char* uB = uA + 8192;
            gload16(gA0 + ke, uA);
            gload16(gA1 + ke, uA + 1024);
            gload16(gB0 + ke, uB);
            gload16(gB1 + ke, uB + 1024);
        };

        f32x4_t acc[4][4];
#pragma unroll
        for (int m = 0; m < 4; ++m)
#pragma unroll
            for (int n = 0; n < 4; ++n)
                acc[m][n] = (f32x4_t){0.f, 0.f, 0.f, 0.f};

        auto mf16 = [&]() {
            __builtin_amdgcn_s_setprio(1);
#pragma unroll
            for (int m = 0; m < 4; ++m)
#pragma unroll
                for (int n = 0; n < 4; ++n)
                    acc[m][n] = __builtin_amdgcn_mfma_f32_16x16x32_bf16(
                        af[m], bv[n], acc[m][n], 0, 0, 0);
            __builtin_amdgcn_s_setprio(0);
        };

        if (pass) BAR();   // all waves done reading LDS from pass 0
        stage2(0, 0, 0); stage2(0, 1, 0);
        VM4_BAR();

        int kt = 0;
        for (; kt < nkt - 1; ++kt) {
            const int buf = kt & 1, nb = buf ^ 1;
            dsAB(buf, 0);
            stage2(nb, 0, kt + 1);
            BAR_LGKM(); SB0();
            mf16(); SB0();
            VM4_BAR();
            dsAB(buf, 1);
            stage2(nb, 1, kt + 1);
            BAR_LGKM(); SB0();
            mf16(); SB0();
            VM4_BAR();
        }
        {
            const int buf = kt & 1;
            dsAB(buf, 0);
            BAR_LGKM(); SB0();
            mf16(); SB0();
            VM0_BAR();
            dsAB(buf, 1);
            BAR_LGKM(); SB0();
            mf16(); SB0();
        }

#pragma unroll
        for (int m = 0; m < 4; ++m)
#pragma unroll
            for (int n = 0; n < 4; ++n)
#pragma unroll
                for (int j = 0; j < 4; ++j) {
                    const int row = row0 + wrM + m * 16 + lg * 4 + j;
                    const int col = col0 + wcN + n * 16 + lr;
                    const long long idx = (long long)row * ldc + col;
                    Cf[idx] = acc[m][n][j] + R[idx];
                }
    }
}

// ------------- transpose + fp32->bf16 convert: in [R][Cc] -> out [Cc][R] ----
__global__ __launch_bounds__(256) void tconv_k(
    const float* __restrict__ in, unsigned short* __restrict__ out,
    int R, int Cc)
{
    __shared__ float t[64][65];
    const int r0 = blockIdx.y * 64, c0 = blockIdx.x * 64;
    const int tid = threadIdx.x;
    const int a = tid >> 4;
    const int b = tid & 15;
#pragma unroll
    for (int i = 0; i < 4; ++i) {
        const int row = a + i * 16;
        float4 v = *(const float4*)(in + (long long)(r0 + row) * Cc + c0 + b * 4);
        t[row][b * 4 + 0] = v.x; t[row][b * 4 + 1] = v.y;
        t[row][b * 4 + 2] = v.z; t[row][b * 4 + 3] = v.w;
    }
    __syncthreads();
#pragma unroll
    for (int i = 0; i < 4; ++i) {
        const int oc = a + i * 16;
        ushort4 o;
        o.x = f2bf(t[b * 4 + 0][oc]);
        o.y = f2bf(t[b * 4 + 1][oc]);
        o.z = f2bf(t[b * 4 + 2][oc]);
        o.w = f2bf(t[b * 4 + 3][oc]);
        *(ushort4*)(out + (long long)(c0 + oc) * R + r0 + b * 4) = o;
    }
}

// ---------------- LayerNorm: one wave per 1024-elem row ---------------------
__global__ __launch_bounds__(256) void ln_k(
    const float* __restrict__ x, const float* __restrict__ g,
    const float* __restrict__ be, unsigned short* __restrict__ out)
{
    const int wv = threadIdx.x >> 6, lane = threadIdx.x & 63;
    const long long row = blockIdx.x * 4 + wv;
    const float* xr = x + row * 1024;
    float4 v[4];
    float s = 0.f, q = 0.f;
#pragma unroll
    for (int j = 0; j < 4; ++j) {
        v[j] = *(const float4*)(xr + j * 256 + lane * 4);
        s += v[j].x + v[j].y + v[j].z + v[j].w;
        q += v[j].x * v[j].x + v[j].y * v[j].y + v[j].z * v[j].z + v[j].w * v[j].w;
    }
#pragma unroll
    for (int off = 32; off > 0; off >>= 1) {
        s += __shfl_xor(s, off);
        q += __shfl_xor(q, off);
    }
    const float mean = s * (1.0f / 1024.0f);
    const float var  = q * (1.0f / 1024.0f) - mean * mean;
    const float rstd = rsqrtf(var + 1e-5f);
#pragma unroll
    for (int j = 0; j < 4; ++j) {
        float4 gv = *(const float4*)(g + j * 256 + lane * 4);
        float4 bv = *(const float4*)(be + j * 256 + lane * 4);
        ushort4 o;
        o.x = f2bf((v[j].x - mean) * rstd * gv.x + bv.x);
        o.y = f2bf((v[j].y - mean) * rstd * gv.y + bv.y);
        o.z = f2bf((v[j].z - mean) * rstd * gv.z + bv.z);
        o.w = f2bf((v[j].w - mean) * rstd * gv.w + bv.w);
        *(ushort4*)(out + row * 1024 + j * 256 + lane * 4) = o;
    }
}

// ------- causal row softmax: warp-per-row, register-resident ---------------
__global__ __launch_bounds__(256) void softmax_k(
    const unsigned short* __restrict__ S, unsigned short* __restrict__ P, int T)
{
    const int wv = threadIdx.x >> 6, lane = threadIdx.x & 63;
    const int t = blockIdx.x * 4 + wv;
    const long long base = ((long long)blockIdx.y * T + t) * (long long)T;
    const unsigned short* srow = S + base;
    unsigned short* prow = P + base;
    const int n = t + 1;
    const int lim = ((t >> 7) + 1) << 7;       // 128-multiple <= T
    const int nch = (lim + 511) >> 9;          // chunks of 512 elems

    float v[4][8];
    float mx = -3.0e38f;
#pragma unroll
    for (int j = 0; j < 4; ++j) {
        if (j < nch) {
            const int e0 = (j * 64 + lane) * 8;
            int4 r = *(const int4*)(srow + e0);
            const unsigned short* u = (const unsigned short*)&r;
#pragma unroll
            for (int i = 0; i < 8; ++i) {
                float f = bf2f(u[i]);
                v[j][i] = f;
                if (e0 + i < n) mx = fmaxf(mx, f);
            }
        }
    }
#pragma unroll
    for (int off = 32; off > 0; off >>= 1) mx = fmaxf(mx, __shfl_xor(mx, off));

    float sum = 0.f;
#pragma unroll
    for (int j = 0; j < 4; ++j) {
        if (j < nch) {
            const int e0 = (j * 64 + lane) * 8;
#pragma unroll
            for (int i = 0; i < 8; ++i) {
                float e = (e0 + i < n) ? __expf(v[j][i] - mx) : 0.f;
                v[j][i] = e;
                sum += e;
            }
        }
    }
#pragma unroll
    for (int off = 32; off > 0; off >>= 1) sum += __shfl_xor(sum, off);
    const float inv = 1.0f / sum;

#pragma unroll
    for (int j = 0; j < 4; ++j) {
        if (j < nch) {
            const int e0 = (j * 64 + lane) * 8;
            unsigned short o[8];
#pragma unroll
            for (int i = 0; i < 8; ++i) o[i] = f2bf(v[j][i] * inv);
            *(int4*)(prow + e0) = *(const int4*)o;
        }
    }
}

// ---------------------------------------------------------------------------
extern "C" void kernel_launch(void* const* d_in, const int* in_sizes, int n_in,
                              void* d_out, int out_size, void* d_ws, size_t ws_size,
                              hipStream_t stream)
{
    const int B = 4, T = 2048, C = 1024, F = 4096;
    const float* x   = (const float*)d_in[0];
    const float* Wk  = (const float*)d_in[1];
    const float* Wq  = (const float*)d_in[2];
    const float* Wv  = (const float*)d_in[3];
    const float* W1  = (const float*)d_in[4];
    const float* b1  = (const float*)d_in[5];
    const float* W2  = (const float*)d_in[6];
    const float* b2  = (const float*)d_in[7];
    const float* g1  = (const float*)d_in[8];
    const float* be1 = (const float*)d_in[9];
    const float* g2  = (const float*)d_in[10];
    const float* be2 = (const float*)d_in[11];

    char* ws = (char*)d_ws;
    const size_t MB = 1ull << 20;
    unsigned short* h    = (unsigned short*)(ws + 0);         // 16 MiB
    unsigned short* qk   = (unsigned short*)(ws + 16 * MB);   // 32 MiB [8192][2048]
    unsigned short* vT   = (unsigned short*)(ws + 64 * MB);   // 16 MiB [1024][8192]
    float*          xres = (float*)(ws + 80 * MB);            // 32 MiB
    unsigned short* S    = (unsigned short*)(ws + 112 * MB);  // 32 MiB bf16 [B][T][T]
    unsigned short* P    = (unsigned short*)(ws + 144 * MB);  // 32 MiB
    unsigned short* ff1  = (unsigned short*)(ws + 112 * MB);  // 64 MiB (aliases S+P)
    unsigned short* wqkT = (unsigned short*)(ws + 176 * MB);  // 4 MiB [2C][C]
    unsigned short* wvT  = (unsigned short*)(ws + 180 * MB);  // 2 MiB [C][C]
    unsigned short* w1T  = (unsigned short*)(ws + 182 * MB);  // 8 MiB [F][C]
    unsigned short* w2T  = (unsigned short*)(ws + 190 * MB);  // 8 MiB [C][F]

    // transposed weight converts
    tconv_k<<<dim3(16, 16), 256, 0, stream>>>(Wq, wqkT, C, C);
    tconv_k<<<dim3(16, 16), 256, 0, stream>>>(Wk, wqkT + C * C, C, C);
    tconv_k<<<dim3(16, 16), 256, 0, stream>>>(Wv, wvT, C, C);
    tconv_k<<<dim3(64, 16), 256, 0, stream>>>(W1, w1T, C, F);
    tconv_k<<<dim3(16, 64), 256, 0, stream>>>(W2, w2T, F, C);

    // LN1
    ln_k<<<dim3(B * T / 4), 256, 0, stream>>>(x, g1, be1, h);

    // [q|k] = h @ [Wq|Wk]   (M=8192, N=2048, K=1024) -> 256 blocks = 1 round
    dim3 gqk(2 * C / 256, (B * T) / 256, 1);
    gemm256<EPI_BF16, false, false><<<gqk, 512, 0, stream>>>(
        h, wqkT, qk, nullptr, nullptr, B * T, 2 * C, C, C, C, 1.0f, 0, 0, 0, 0);

    // fused: S = q@k^T/32 (causal tiles) + vT = Wv^T@h^T (dead-block remap)
    sc_vt_k<<<dim3(8, 9, B), 512, 0, stream>>>(qk, wvT, h, S, vT);

    // P = causal softmax(S), warp-per-row
    softmax_k<<<dim3(T / 4, B), 256, 0, stream>>>(S, P, T);

    // xres = x + P @ v : paired-KLIM engine, 256 balanced blocks
    pv_k<<<dim3(C / 128, 8, B), 256, 0, stream>>>(
        P, vT, xres, x, T, C, B * T);

    // LN2
    ln_k<<<dim3(B * T / 4), 256, 0, stream>>>(xres, g2, be2, h);

    // ff1 = relu(h @ W1 + b1)   (M=8192, N=4096, K=1024) -> 512 blocks @256²
    dim3 gf1(F / 256, (B * T) / 256, 1);
    gemm256<EPI_BIAS_RELU_BF16, false, false><<<gf1, 512, 0, stream>>>(
        h, w1T, ff1, b1, nullptr, B * T, F, C, C, C, 1.0f, 0, 0, 0, 0);

    // out = xres + ff1 @ W2 + b2   (M=8192, N=1024, K=4096) -> 512 blocks @128²
    dim3 gf2(C / 128, (B * T) / 128, 1);
    gemm128<EPI_BIAS_RESID_F32, false, false><<<gf2, 256, 0, stream>>>(
        ff1, w2T, (float*)d_out, b2, xres, B * T, C, F, F, F, 1.0f, 0, 0, 0, 0);
}